// Round 6
// baseline (601.103 us; speedup 1.0000x reference)
//
#include <hip/hip_runtime.h>

// ---------------------------------------------------------------------------
// RelPositionMultiHeadedAttention (Conformer / Transformer-XL rel-shift)
// B=4, T=2048, C=512, H=8, D=64
//
// R14: attn de-staged (GEMM/prepass = R12-exact).
//  - K and P B-frags load DIRECT from global (L2-resident: 768KB/bh, ~3MB/XCD
//    < 4MB L2). k_s/pA LDS staging deleted.
//  - LDS = msw only (11264 B, wave-private row-major [64][88], R8-verified
//    skew/gather/weight indexing). Wave-private => NO __syncthreads in the
//    j-loop at all; waves drift and hide each other's latency.
//  - Occupancy is grid-limited (4096 waves = 16/CU), so launch_bounds(256,4)
//    (VGPR cap 128) -- no spill risk (R11 lesson).
// ---------------------------------------------------------------------------

#define Bb 4
#define Tt 2048
#define Cc 512
#define Hh 8
#define Dd 64

typedef __bf16 bf16_t;
typedef __bf16 bf16x8 __attribute__((ext_vector_type(8)));
typedef __bf16 bf16x4 __attribute__((ext_vector_type(4)));
typedef float  f32x4  __attribute__((ext_vector_type(4)));

// ---------------------------------------------------------------------------
// Prepass: WT_hi[n][k], WT_lo[n][k] bf16 from W[k][n] f32.
// ---------------------------------------------------------------------------
__global__ __launch_bounds__(256, 4)
void wsplit_kernel(const float* __restrict__ Wq, const float* __restrict__ Wk,
                   const float* __restrict__ Wv, const float* __restrict__ Wp,
                   const float* __restrict__ Wo,
                   bf16_t* __restrict__ WT4, bf16_t* __restrict__ WoT, int mode)
{
    const int w = (mode < 0) ? (int)blockIdx.y : 4;
    const float* W = (w == 0) ? Wq : (w == 1) ? Wk : (w == 2) ? Wv : (w == 3) ? Wp : Wo;
    bf16_t* dh = (w == 4) ? WoT : WT4 + (size_t)w * 2 * 262144;
    bf16_t* dl = dh + 262144;

    const int tile = blockIdx.x;           // 64 tiles of 64x64
    const int k0 = (tile >> 3) * 64;
    const int n0 = (tile & 7) * 64;
    const int tid = threadIdx.x;

    __shared__ bf16_t th[64][66];
    __shared__ bf16_t tl[64][66];

#pragma unroll
    for (int rep = 0; rep < 4; rep++) {
        int id = rep * 256 + tid;          // 1024 ids: 64 k-rows x 16 f32x4 segs
        int kk = id >> 4, ns = id & 15;
        f32x4 v = *(const f32x4*)&W[(size_t)(k0 + kk) * 512 + n0 + ns * 4];
#pragma unroll
        for (int e = 0; e < 4; e++) {
            bf16_t h = (bf16_t)v[e];
            th[kk][ns * 4 + e] = h;
            tl[kk][ns * 4 + e] = (bf16_t)(v[e] - (float)h);
        }
    }
    __syncthreads();
#pragma unroll
    for (int rep = 0; rep < 2; rep++) {
        int id = rep * 256 + tid;          // 512 ids: 64 n-rows x 8 k-segs
        int nn = id >> 3, ks = id & 7;
        bf16x8 hv, lv;
#pragma unroll
        for (int j = 0; j < 8; j++) { hv[j] = th[ks * 8 + j][nn]; lv[j] = tl[ks * 8 + j][nn]; }
        *(bf16x8*)&dh[(size_t)(n0 + nn) * 512 + k0 + ks * 8] = hv;
        *(bf16x8*)&dl[(size_t)(n0 + nn) * 512 + k0 + ks * 8] = lv;
    }
}

// ---------------------------------------------------------------------------
// Split-bf16 MFMA GEMM: Y = X @ W (+bias). X [8192,512] fp32 (converted at
// staging), W via prepass bf16 hi/lo planes WT[n][k]. 2-phase reg-staged.
// ---------------------------------------------------------------------------
__global__ __launch_bounds__(256, 2)
void split_gemm_kernel(const float* __restrict__ Xq, const float* __restrict__ Xk,
                       const float* __restrict__ Xv, const float* __restrict__ Xp,
                       const float* __restrict__ Xc,
                       const bf16_t* __restrict__ WT4, const bf16_t* __restrict__ WoT,
                       const float* __restrict__ bq, const float* __restrict__ bk,
                       const float* __restrict__ bv, const float* __restrict__ bo,
                       const float* __restrict__ bias_u, const float* __restrict__ bias_v,
                       bf16_t* __restrict__ QU, bf16_t* __restrict__ QV,
                       bf16_t* __restrict__ K16, bf16_t* __restrict__ VT16,
                       bf16_t* __restrict__ P16, float* __restrict__ OUT,
                       int modeArg)
{
    const int z = (modeArg < 0) ? blockIdx.z : modeArg;
    const float* X    = (z == 0) ? Xq : (z == 1) ? Xk : (z == 2) ? Xv : (z == 3) ? Xp : Xc;
    const bf16_t* Wh  = (z == 4) ? WoT : WT4 + (size_t)z * 2 * 262144;
    const bf16_t* Wl  = Wh + 262144;
    const float* bias = (z == 0) ? bq : (z == 1) ? bk : (z == 2) ? bv : (z == 3) ? nullptr : bo;

    const int bx = blockIdx.x;
    const int g  = bx >> 3, x8 = bx & 7;
    const int mtile = (g >> 2) * 8 + x8;   // 0..63
    const int ntile = g & 3;               // 0..3
    const int r0 = mtile * 128;
    const int c0 = ntile * 128;

    const int tid  = threadIdx.x;
    const int wave = tid >> 6;
    const int lane = tid & 63;
    const int quad = lane >> 4;
    const int l16  = lane & 15;
    const int rb = (wave >> 1) * 64;
    const int cb = (wave & 1) * 64;

    __shared__ __align__(16) bf16_t Ah[128][72];
    __shared__ __align__(16) bf16_t Al[128][72];
    __shared__ __align__(16) bf16_t Bh[128][72];
    __shared__ __align__(16) bf16_t Bl[128][72];

    f32x4 acc[4][4];
#pragma unroll
    for (int mt = 0; mt < 4; mt++)
#pragma unroll
        for (int nt = 0; nt < 4; nt++)
#pragma unroll
            for (int r = 0; r < 4; r++) acc[mt][nt][r] = 0.f;

    // staged-tile registers
    f32x4  xa[8];
    bf16x8 wbh[4], wbl[4];

    // prologue: load K-step 0
#pragma unroll
    for (int rep = 0; rep < 8; rep++) {
        int id = rep * 256 + tid;          // 2048 ids: 128 rows x 16 f32x4 segs
        int m = id >> 4, c = id & 15;
        xa[rep] = *(const f32x4*)&X[(size_t)(r0 + m) * 512 + c * 4];
    }
#pragma unroll
    for (int rep = 0; rep < 4; rep++) {
        int id = rep * 256 + tid;          // 1024 ids: 128 rows x 8 k-segs
        int n = id >> 3, seg = id & 7;
        wbh[rep] = *(const bf16x8*)&Wh[(size_t)(c0 + n) * 512 + seg * 8];
        wbl[rep] = *(const bf16x8*)&Wl[(size_t)(c0 + n) * 512 + seg * 8];
    }

    for (int it = 0; it < 8; ++it) {
        // write staged regs to LDS (conversion happens here, once/element)
#pragma unroll
        for (int rep = 0; rep < 8; rep++) {
            int id = rep * 256 + tid;
            int m = id >> 4, c = id & 15;
            f32x4 v = xa[rep];
            bf16x4 hh, ll;
#pragma unroll
            for (int e = 0; e < 4; e++) {
                bf16_t hv = (bf16_t)v[e];
                hh[e] = hv;
                ll[e] = (bf16_t)(v[e] - (float)hv);
            }
            *(bf16x4*)&Ah[m][c * 4] = hh;
            *(bf16x4*)&Al[m][c * 4] = ll;
        }
#pragma unroll
        for (int rep = 0; rep < 4; rep++) {
            int id = rep * 256 + tid;
            int n = id >> 3, seg = id & 7;
            *(bf16x8*)&Bh[n][seg * 8] = wbh[rep];
            *(bf16x8*)&Bl[n][seg * 8] = wbl[rep];
        }
        __syncthreads();

        // prefetch next K-step into regs (in flight under the MFMAs below)
        if (it < 7) {
            const int k0n = (it + 1) * 64;
#pragma unroll
            for (int rep = 0; rep < 8; rep++) {
                int id = rep * 256 + tid;
                int m = id >> 4, c = id & 15;
                xa[rep] = *(const f32x4*)&X[(size_t)(r0 + m) * 512 + k0n + c * 4];
            }
#pragma unroll
            for (int rep = 0; rep < 4; rep++) {
                int id = rep * 256 + tid;
                int n = id >> 3, seg = id & 7;
                wbh[rep] = *(const bf16x8*)&Wh[(size_t)(c0 + n) * 512 + k0n + seg * 8];
                wbl[rep] = *(const bf16x8*)&Wl[(size_t)(c0 + n) * 512 + k0n + seg * 8];
            }
        }

        // compute on LDS tile
#pragma unroll
        for (int kc = 0; kc < 2; kc++) {
            bf16x8 bh[4], bl[4], ah[4], al[4];
#pragma unroll
            for (int nt = 0; nt < 4; nt++) {
                bh[nt] = *(const bf16x8*)&Bh[cb + nt * 16 + l16][kc * 32 + quad * 8];
                bl[nt] = *(const bf16x8*)&Bl[cb + nt * 16 + l16][kc * 32 + quad * 8];
            }
#pragma unroll
            for (int mt = 0; mt < 4; mt++) {
                ah[mt] = *(const bf16x8*)&Ah[rb + mt * 16 + l16][kc * 32 + quad * 8];
                al[mt] = *(const bf16x8*)&Al[rb + mt * 16 + l16][kc * 32 + quad * 8];
            }
#pragma unroll
            for (int mt = 0; mt < 4; mt++) {
#pragma unroll
                for (int nt = 0; nt < 4; nt++) {
                    acc[mt][nt] = __builtin_amdgcn_mfma_f32_16x16x32_bf16(ah[mt], bh[nt], acc[mt][nt], 0, 0, 0);
                    acc[mt][nt] = __builtin_amdgcn_mfma_f32_16x16x32_bf16(ah[mt], bl[nt], acc[mt][nt], 0, 0, 0);
                    acc[mt][nt] = __builtin_amdgcn_mfma_f32_16x16x32_bf16(al[mt], bh[nt], acc[mt][nt], 0, 0, 0);
                }
            }
        }
        __syncthreads();
    }

#pragma unroll
    for (int mt = 0; mt < 4; mt++) {
#pragma unroll
        for (int r = 0; r < 4; r++) {
            int row = r0 + rb + mt * 16 + quad * 4 + r;
#pragma unroll
            for (int nt = 0; nt < 4; nt++) {
                int col = c0 + cb + nt * 16 + l16;
                float y = acc[mt][nt][r] + (bias ? bias[col] : 0.f);
                if (z == 4) {
                    OUT[(size_t)row * 512 + col] = y;
                } else {
                    int b = row >> 11, t = row & 2047;
                    int h = col >> 6,  d = col & 63;
                    if (z == 0) {
                        size_t idx = (((size_t)(b * Hh + h)) * Tt + t) * Dd + d;
                        QU[idx] = (bf16_t)(y + bias_u[col]);
                        QV[idx] = (bf16_t)(y + bias_v[col]);
                    } else if (z == 1) {
                        size_t idx = (((size_t)(b * Hh + h)) * Tt + t) * Dd + d;
                        K16[idx] = (bf16_t)y;
                    } else if (z == 2) {
                        // transposed: VT[bh][d][t]
                        size_t idx = (((size_t)(b * Hh + h)) * Dd + d) * Tt + t;
                        VT16[idx] = (bf16_t)y;
                    } else {
                        size_t idx = (((size_t)(b * Hh + h)) * Tt + t) * Dd + d;
                        P16[idx] = (bf16_t)y;
                    }
                }
            }
        }
    }
}

// ---------------------------------------------------------------------------
// Kernel 2: attention, de-staged. grid = (bh=32, itile=32).
// LDS = msw only: [64][88] bf16 (11264 B), wave-private strips, STRIP-LOCAL
// skewed pos scores (R8-verified indexing); softmax weights clobber cols
// 0..63 strictly after the gathers. K/P/V operands all direct from global
// (L2-resident). NO __syncthreads in the j-loop.
// ---------------------------------------------------------------------------
__global__ __launch_bounds__(256, 4)
void attn_kernel(const bf16_t* __restrict__ QU, const bf16_t* __restrict__ QV,
                 const bf16_t* __restrict__ K16, const bf16_t* __restrict__ VT16,
                 const bf16_t* __restrict__ P16, float* __restrict__ CTX)
{
    const int bh = blockIdx.x;                 // XCD locality: linear%8 = bh%8
    const int i0 = blockIdx.y * 64;
    const int b = bh >> 3, h = bh & 7;
    const int tid = threadIdx.x;
    const int wave = tid >> 6;
    const int lane = tid & 63;
    const int quad = lane >> 4;
    const int l16 = lane & 15;

    const bf16_t* qu_g = QU + (size_t)bh * Tt * Dd;
    const bf16_t* qv_g = QV + (size_t)bh * Tt * Dd;
    const bf16_t* k_g  = K16 + (size_t)bh * Tt * Dd;
    const bf16_t* vt_g = VT16 + (size_t)bh * Dd * Tt;   // [d][t]
    const bf16_t* p_g  = P16 + (size_t)bh * Tt * Dd;

    __shared__ __align__(16) bf16_t msw[64][88];        // wave-private strips

    const int off_w = 48 - wave * 16;          // strip-local = absolute - off_w
    const int cmin = 48 - wave * 16;           // absolute strip window
    const int cmax = 126 - wave * 16;

    // A-operand fragments, direct global loads: A[m=l16][k=quad*8+e]
    const int qrow = i0 + wave * 16 + l16;
    const int qrow2 = (qrow + 1 > Tt - 1) ? (Tt - 1) : (qrow + 1);  // clamped row never gathered
    bf16x8 aq[2], av1[2], av2[2];
#pragma unroll
    for (int kc = 0; kc < 2; kc++) {
        aq[kc]  = *(const bf16x8*)(qu_g + (size_t)qrow  * Dd + kc * 32 + quad * 8);
        av1[kc] = *(const bf16x8*)(qv_g + (size_t)qrow  * Dd + kc * 32 + quad * 8);
        av2[kc] = *(const bf16x8*)(qv_g + (size_t)qrow2 * Dd + kc * 32 + quad * 8);
    }

    float lsum[4];
    f32x4 accO[4];
#pragma unroll
    for (int r = 0; r < 4; r++) lsum[r] = 0.f;
#pragma unroll
    for (int dt = 0; dt < 4; dt++)
#pragma unroll
        for (int r = 0; r < 4; r++) accO[dt][r] = 0.f;

    for (int j0 = 0; j0 < Tt; j0 += 64) {
        int d_lo = i0 - (j0 + 63);
        int d_hi = i0 + 63 - j0;
        int w1 = 0, prow1 = 0;
        if (d_hi >= 0) {
            int b1 = d_lo > 0 ? d_lo : 0;
            w1 = d_hi - b1 + 1;
            prow1 = (Tt - 1) - d_hi;
        }
        int dmax2 = d_hi < -2 ? d_hi : -2;
        int w2 = 0, e_lo = 0;
        if (d_lo <= dmax2) {
            e_lo = -dmax2 - 2;
            int e_hi = -d_lo - 2;
            w2 = e_hi - e_lo + 1;
        }
        int c2_0 = d_hi + 2 + e_lo;
        int nct1 = (w1 + 15) >> 4;
        int nct2 = (w2 + 15) >> 4;

        // content scores: K B-frags direct from global (natural [t][d] layout)
        f32x4 accS[4];
#pragma unroll
        for (int nt = 0; nt < 4; nt++) {
            f32x4 acc = {0.f, 0.f, 0.f, 0.f};
#pragma unroll
            for (int kc = 0; kc < 2; kc++) {
                bf16x8 bk8 = *(const bf16x8*)(k_g + (size_t)(j0 + nt * 16 + l16) * Dd + kc * 32 + quad * 8);
                acc = __builtin_amdgcn_mfma_f32_16x16x32_bf16(aq[kc], bk8, acc, 0, 0, 0);
            }
            accS[nt] = acc;
        }

        // banded pos matmul -> strip-local skewed store (wave-private).
        // P B-frags direct from global; srcrow replicates the staged mapping
        // (rows >= w1+w2 were stale/never-gathered before; clamp keeps them
        // in-bounds -- gathered (row,col) set is index-determined, unchanged).
        for (int ct = 0; ct < nct1 + nct2; ct++) {
            bool b2 = ct >= nct1;
            int rb_ = b2 ? (w1 + (ct - nct1) * 16) : (ct * 16);
            int cb_ = b2 ? (c2_0 + (ct - nct1) * 16) : (ct * 16);
            if (cb_ > cmax || cb_ + 15 < cmin) continue;
            int rr = rb_ + l16;
            int srcrow = (rr < w1) ? (prow1 + rr) : (e_lo + rr - w1);
            if (srcrow > Tt - 1) srcrow = Tt - 1;
            f32x4 acc = {0.f, 0.f, 0.f, 0.f};
#pragma unroll
            for (int kc = 0; kc < 2; kc++) {
                bf16x8 bp = *(const bf16x8*)(p_g + (size_t)srcrow * Dd + kc * 32 + quad * 8);
                acc = b2 ? __builtin_amdgcn_mfma_f32_16x16x32_bf16(av2[kc], bp, acc, 0, 0, 0)
                         : __builtin_amdgcn_mfma_f32_16x16x32_bf16(av1[kc], bp, acc, 0, 0, 0);
            }
            int colp = cb_ + l16 - off_w;          // strip-local
            if ((unsigned)colp < 80u) {
#pragma unroll
                for (int r = 0; r < 4; r++)
                    msw[wave * 16 + quad * 4 + r][colp] = (bf16_t)acc[r];
            }
        }
        // zero column for dd == -1 (strip-local)
        {
            int zcl = d_hi + 1 - off_w;
            if ((unsigned)zcl < 80u && quad == 0)
                msw[wave * 16 + l16][zcl] = (bf16_t)0.f;
        }

        // gather all 16 (no aliasing stores in between), then write weights
        float wv[4][4];
#pragma unroll
        for (int nt = 0; nt < 4; nt++) {
#pragma unroll
            for (int r = 0; r < 4; r++) {
                float pos = (float)msw[wave * 16 + quad * 4 + r]
                                    [nt * 16 + l16 + 15 - (quad * 4 + r)];
                float x = accS[nt][r] + pos;
                float a = fminf(fmaf(x, 0.18033688f, -17.3123405f), 120.0f);
                float w = exp2f(a);
                lsum[r] += w;
                wv[nt][r] = w;
            }
        }
#pragma unroll
        for (int nt = 0; nt < 4; nt++)
#pragma unroll
            for (int r = 0; r < 4; r++)
                msw[wave * 16 + quad * 4 + r][nt * 16 + l16] = (bf16_t)wv[nt][r];

        // O += W @ V : A from own msw strip, B direct from VT ([d][t])
#pragma unroll
        for (int kc = 0; kc < 2; kc++) {
            bf16x8 aw = *(const bf16x8*)&msw[wave * 16 + l16][kc * 32 + quad * 8];
#pragma unroll
            for (int dt = 0; dt < 4; dt++) {
                bf16x8 bv8 = *(const bf16x8*)(vt_g + (size_t)(dt * 16 + l16) * Tt + j0 + kc * 32 + quad * 8);
                accO[dt] = __builtin_amdgcn_mfma_f32_16x16x32_bf16(aw, bv8, accO[dt], 0, 0, 0);
            }
        }
        // no barrier: msw is wave-private; K/P/V are read-only global
    }

#pragma unroll
    for (int r = 0; r < 4; r++) {
#pragma unroll
        for (int off = 1; off < 16; off <<= 1) lsum[r] += __shfl_xor(lsum[r], off, 64);
    }

#pragma unroll
    for (int r = 0; r < 4; r++) {
        int il = wave * 16 + quad * 4 + r;
        int ig = i0 + il;
        float inv = 1.0f / lsum[r];
#pragma unroll
        for (int dt = 0; dt < 4; dt++) {
            CTX[((size_t)(b * Tt + ig)) * Cc + h * Dd + dt * 16 + l16] = accO[dt][r] * inv;
        }
    }
}

// ---------------------------------------------------------------------------
extern "C" void kernel_launch(void* const* d_in, const int* in_sizes, int n_in,
                              void* d_out, int out_size, void* d_ws, size_t ws_size,
                              hipStream_t stream)
{
    const float* query = (const float*)d_in[0];
    const float* key   = (const float*)d_in[1];
    const float* value = (const float*)d_in[2];
    const float* pemb  = (const float*)d_in[3];
    const float* Wq    = (const float*)d_in[4];
    const float* bq    = (const float*)d_in[5];
    const float* Wk    = (const float*)d_in[6];
    const float* bk    = (const float*)d_in[7];
    const float* Wv    = (const float*)d_in[8];
    const float* bv    = (const float*)d_in[9];
    const float* Wpos  = (const float*)d_in[10];
    const float* pbu   = (const float*)d_in[11];
    const float* pbv   = (const float*)d_in[12];
    const float* Wo    = (const float*)d_in[13];
    const float* bo    = (const float*)d_in[14];

    const size_t NE = (size_t)Bb * Hh * Tt * Dd;  // 4,194,304 per tensor
    bf16_t* QU   = (bf16_t*)d_ws;
    bf16_t* QV   = QU + NE;
    bf16_t* K16  = QV + NE;
    bf16_t* VT16 = K16 + NE;
    bf16_t* P16  = VT16 + NE;
    float*  CTX  = (float*)(P16 + NE);            // ws >= 56 MB (unchanged)

    // W^T hi/lo planes overlaid on dead regions (no extra workspace):
    //  - WT4 (Wq,Wk,Wv,Wpos; 4 MB) in CTX region: dead until attn writes CTX.
    //  - WoT (1 MB) in QU region: written AFTER attn (QU dead by then).
    bf16_t* WT4 = (bf16_t*)CTX;
    bf16_t* WoT = (bf16_t*)QU;

    // prepass A: Wq/Wk/Wv/Wpos -> transposed hi/lo bf16 planes
    wsplit_kernel<<<dim3(64, 4), 256, 0, stream>>>(Wq, Wk, Wv, Wpos, Wo, WT4, WoT, -1);

    // QKVP projections (z = blockIdx.z)
    split_gemm_kernel<<<dim3(256, 1, 4), 256, 0, stream>>>(
        query, key, value, pemb, CTX, WT4, WoT,
        bq, bk, bv, bo, pbu, pbv, QU, QV, K16, VT16, P16, (float*)d_out, -1);

    attn_kernel<<<dim3(32, 32), 256, 0, stream>>>(QU, QV, K16, VT16, P16, CTX);

    // prepass B: Wo -> WoT (QU region now dead)
    wsplit_kernel<<<dim3(64, 1), 256, 0, stream>>>(Wq, Wk, Wv, Wpos, Wo, WT4, WoT, 4);

    // output projection (mode 4)
    split_gemm_kernel<<<dim3(256, 1, 1), 256, 0, stream>>>(
        query, key, value, pemb, CTX, WT4, WoT,
        bq, bk, bv, bo, pbu, pbv, QU, QV, K16, VT16, P16, (float*)d_out, 4);
}

// Round 7
// 477.259 us; speedup vs baseline: 1.2595x; 1.2595x over previous
//
#include <hip/hip_runtime.h>

// ---------------------------------------------------------------------------
// RelPositionMultiHeadedAttention (Conformer / Transformer-XL rel-shift)
// B=4, T=2048, C=512, H=8, D=64
//
// R15: attn = R12-exact (verified 226us). GEMM: B-frags DIRECT from global
// (prepass WT[n][k] is already fragment-layout, L2-resident, reused 8x);
// Bh/Bl LDS planes deleted -> LDS 36864 B, launch_bounds(256,3), 12 waves/CU.
// B loads have no LDS dependency => issue across barriers; barrier drain now
// covers only the A staging. A-path keeps R12 reg-prefetch.
// ---------------------------------------------------------------------------

#define Bb 4
#define Tt 2048
#define Cc 512
#define Hh 8
#define Dd 64

typedef __bf16 bf16_t;
typedef __bf16 bf16x8 __attribute__((ext_vector_type(8)));
typedef __bf16 bf16x4 __attribute__((ext_vector_type(4)));
typedef float  f32x4  __attribute__((ext_vector_type(4)));

// ---------------------------------------------------------------------------
// Prepass: WT_hi[n][k], WT_lo[n][k] bf16 from W[k][n] f32.
// ---------------------------------------------------------------------------
__global__ __launch_bounds__(256, 4)
void wsplit_kernel(const float* __restrict__ Wq, const float* __restrict__ Wk,
                   const float* __restrict__ Wv, const float* __restrict__ Wp,
                   const float* __restrict__ Wo,
                   bf16_t* __restrict__ WT4, bf16_t* __restrict__ WoT, int mode)
{
    const int w = (mode < 0) ? (int)blockIdx.y : 4;
    const float* W = (w == 0) ? Wq : (w == 1) ? Wk : (w == 2) ? Wv : (w == 3) ? Wp : Wo;
    bf16_t* dh = (w == 4) ? WoT : WT4 + (size_t)w * 2 * 262144;
    bf16_t* dl = dh + 262144;

    const int tile = blockIdx.x;           // 64 tiles of 64x64
    const int k0 = (tile >> 3) * 64;
    const int n0 = (tile & 7) * 64;
    const int tid = threadIdx.x;

    __shared__ bf16_t th[64][66];
    __shared__ bf16_t tl[64][66];

#pragma unroll
    for (int rep = 0; rep < 4; rep++) {
        int id = rep * 256 + tid;          // 1024 ids: 64 k-rows x 16 f32x4 segs
        int kk = id >> 4, ns = id & 15;
        f32x4 v = *(const f32x4*)&W[(size_t)(k0 + kk) * 512 + n0 + ns * 4];
#pragma unroll
        for (int e = 0; e < 4; e++) {
            bf16_t h = (bf16_t)v[e];
            th[kk][ns * 4 + e] = h;
            tl[kk][ns * 4 + e] = (bf16_t)(v[e] - (float)h);
        }
    }
    __syncthreads();
#pragma unroll
    for (int rep = 0; rep < 2; rep++) {
        int id = rep * 256 + tid;          // 512 ids: 64 n-rows x 8 k-segs
        int nn = id >> 3, ks = id & 7;
        bf16x8 hv, lv;
#pragma unroll
        for (int j = 0; j < 8; j++) { hv[j] = th[ks * 8 + j][nn]; lv[j] = tl[ks * 8 + j][nn]; }
        *(bf16x8*)&dh[(size_t)(n0 + nn) * 512 + k0 + ks * 8] = hv;
        *(bf16x8*)&dl[(size_t)(n0 + nn) * 512 + k0 + ks * 8] = lv;
    }
}

// ---------------------------------------------------------------------------
// Split-bf16 MFMA GEMM: Y = X @ W (+bias). X [8192,512] fp32 (converted at
// staging), W via prepass bf16 hi/lo planes WT[n][k].
// A: reg-prefetch -> LDS (barrier-protected). B: DIRECT global reads.
// ---------------------------------------------------------------------------
__global__ __launch_bounds__(256, 3)
void split_gemm_kernel(const float* __restrict__ Xq, const float* __restrict__ Xk,
                       const float* __restrict__ Xv, const float* __restrict__ Xp,
                       const float* __restrict__ Xc,
                       const bf16_t* __restrict__ WT4, const bf16_t* __restrict__ WoT,
                       const float* __restrict__ bq, const float* __restrict__ bk,
                       const float* __restrict__ bv, const float* __restrict__ bo,
                       const float* __restrict__ bias_u, const float* __restrict__ bias_v,
                       bf16_t* __restrict__ QU, bf16_t* __restrict__ QV,
                       bf16_t* __restrict__ K16, bf16_t* __restrict__ VT16,
                       bf16_t* __restrict__ P16, float* __restrict__ OUT,
                       int modeArg)
{
    const int z = (modeArg < 0) ? blockIdx.z : modeArg;
    const float* X    = (z == 0) ? Xq : (z == 1) ? Xk : (z == 2) ? Xv : (z == 3) ? Xp : Xc;
    const bf16_t* Wh  = (z == 4) ? WoT : WT4 + (size_t)z * 2 * 262144;
    const bf16_t* Wl  = Wh + 262144;
    const float* bias = (z == 0) ? bq : (z == 1) ? bk : (z == 2) ? bv : (z == 3) ? nullptr : bo;

    const int bx = blockIdx.x;
    const int g  = bx >> 3, x8 = bx & 7;
    const int mtile = (g >> 2) * 8 + x8;   // 0..63
    const int ntile = g & 3;               // 0..3
    const int r0 = mtile * 128;
    const int c0 = ntile * 128;

    const int tid  = threadIdx.x;
    const int wave = tid >> 6;
    const int lane = tid & 63;
    const int quad = lane >> 4;
    const int l16  = lane & 15;
    const int rb = (wave >> 1) * 64;
    const int cb = (wave & 1) * 64;

    __shared__ __align__(16) bf16_t Ah[128][72];
    __shared__ __align__(16) bf16_t Al[128][72];

    // B-fragment global row base: WT[n][k] with n = c0 + cb + nt*16 + l16
    const bf16_t* wh_row[4];
    const bf16_t* wl_row[4];
#pragma unroll
    for (int nt = 0; nt < 4; nt++) {
        wh_row[nt] = Wh + (size_t)(c0 + cb + nt * 16 + l16) * 512;
        wl_row[nt] = Wl + (size_t)(c0 + cb + nt * 16 + l16) * 512;
    }

    f32x4 acc[4][4];
#pragma unroll
    for (int mt = 0; mt < 4; mt++)
#pragma unroll
        for (int nt = 0; nt < 4; nt++)
#pragma unroll
            for (int r = 0; r < 4; r++) acc[mt][nt][r] = 0.f;

    // A staged-tile registers (reg-prefetch, R12 pattern)
    f32x4 xa[8];
#pragma unroll
    for (int rep = 0; rep < 8; rep++) {
        int id = rep * 256 + tid;          // 2048 ids: 128 rows x 16 f32x4 segs
        int m = id >> 4, c = id & 15;
        xa[rep] = *(const f32x4*)&X[(size_t)(r0 + m) * 512 + c * 4];
    }

    for (int it = 0; it < 8; ++it) {
        const int k0 = it * 64;
        // write staged A regs to LDS (hi/lo conversion once per element)
#pragma unroll
        for (int rep = 0; rep < 8; rep++) {
            int id = rep * 256 + tid;
            int m = id >> 4, c = id & 15;
            f32x4 v = xa[rep];
            bf16x4 hh, ll;
#pragma unroll
            for (int e = 0; e < 4; e++) {
                bf16_t hv = (bf16_t)v[e];
                hh[e] = hv;
                ll[e] = (bf16_t)(v[e] - (float)hv);
            }
            *(bf16x4*)&Ah[m][c * 4] = hh;
            *(bf16x4*)&Al[m][c * 4] = ll;
        }
        __syncthreads();

        // prefetch next A K-step into regs (in flight under MFMAs below)
        if (it < 7) {
            const int k0n = (it + 1) * 64;
#pragma unroll
            for (int rep = 0; rep < 8; rep++) {
                int id = rep * 256 + tid;
                int m = id >> 4, c = id & 15;
                xa[rep] = *(const f32x4*)&X[(size_t)(r0 + m) * 512 + k0n + c * 4];
            }
        }

        // compute: A from LDS, B direct from global (L2-resident, no barrier dep)
#pragma unroll
        for (int kc = 0; kc < 2; kc++) {
            bf16x8 bh[4], bl[4], ah[4], al[4];
#pragma unroll
            for (int nt = 0; nt < 4; nt++) {
                bh[nt] = *(const bf16x8*)(wh_row[nt] + k0 + kc * 32 + quad * 8);
                bl[nt] = *(const bf16x8*)(wl_row[nt] + k0 + kc * 32 + quad * 8);
            }
#pragma unroll
            for (int mt = 0; mt < 4; mt++) {
                ah[mt] = *(const bf16x8*)&Ah[rb + mt * 16 + l16][kc * 32 + quad * 8];
                al[mt] = *(const bf16x8*)&Al[rb + mt * 16 + l16][kc * 32 + quad * 8];
            }
#pragma unroll
            for (int mt = 0; mt < 4; mt++) {
#pragma unroll
                for (int nt = 0; nt < 4; nt++) {
                    acc[mt][nt] = __builtin_amdgcn_mfma_f32_16x16x32_bf16(ah[mt], bh[nt], acc[mt][nt], 0, 0, 0);
                    acc[mt][nt] = __builtin_amdgcn_mfma_f32_16x16x32_bf16(ah[mt], bl[nt], acc[mt][nt], 0, 0, 0);
                    acc[mt][nt] = __builtin_amdgcn_mfma_f32_16x16x32_bf16(al[mt], bh[nt], acc[mt][nt], 0, 0, 0);
                }
            }
        }
        __syncthreads();
    }

#pragma unroll
    for (int mt = 0; mt < 4; mt++) {
#pragma unroll
        for (int r = 0; r < 4; r++) {
            int row = r0 + rb + mt * 16 + quad * 4 + r;
#pragma unroll
            for (int nt = 0; nt < 4; nt++) {
                int col = c0 + cb + nt * 16 + l16;
                float y = acc[mt][nt][r] + (bias ? bias[col] : 0.f);
                if (z == 4) {
                    OUT[(size_t)row * 512 + col] = y;
                } else {
                    int b = row >> 11, t = row & 2047;
                    int h = col >> 6,  d = col & 63;
                    if (z == 0) {
                        size_t idx = (((size_t)(b * Hh + h)) * Tt + t) * Dd + d;
                        QU[idx] = (bf16_t)(y + bias_u[col]);
                        QV[idx] = (bf16_t)(y + bias_v[col]);
                    } else if (z == 1) {
                        size_t idx = (((size_t)(b * Hh + h)) * Tt + t) * Dd + d;
                        K16[idx] = (bf16_t)y;
                    } else if (z == 2) {
                        // transposed: VT[bh][d][t]
                        size_t idx = (((size_t)(b * Hh + h)) * Dd + d) * Tt + t;
                        VT16[idx] = (bf16_t)y;
                    } else {
                        size_t idx = (((size_t)(b * Hh + h)) * Tt + t) * Dd + d;
                        P16[idx] = (bf16_t)y;
                    }
                }
            }
        }
    }
}

// ---------------------------------------------------------------------------
// Kernel 2: attention (R12-exact, verified 226us). grid = (bh=32, itile=32).
// LDS map (bytes), total 38912:
//   [0,     18432)  pA  [128][72] bf16: P band rows 0..(w1+w2)
//   [18432, 27648)  k_s [64][72]
//   [27648, 38912)  msw [64][88] bf16, wave-private strips, STRIP-LOCAL
//                   skewed pos scores; softmax weights later clobber cols
//                   0..63 (strictly after the gathers).
// ---------------------------------------------------------------------------
__global__ __launch_bounds__(256, 3)
void attn_kernel(const bf16_t* __restrict__ QU, const bf16_t* __restrict__ QV,
                 const bf16_t* __restrict__ K16, const bf16_t* __restrict__ VT16,
                 const bf16_t* __restrict__ P16, float* __restrict__ CTX)
{
    const int bh = blockIdx.x;                 // XCD locality: linear%8 = bh%8
    const int i0 = blockIdx.y * 64;
    const int b = bh >> 3, h = bh & 7;
    const int tid = threadIdx.x;
    const int wave = tid >> 6;
    const int lane = tid & 63;
    const int quad = lane >> 4;
    const int l16 = lane & 15;

    const bf16_t* qu_g = QU + (size_t)bh * Tt * Dd;
    const bf16_t* qv_g = QV + (size_t)bh * Tt * Dd;
    const bf16_t* k_g  = K16 + (size_t)bh * Tt * Dd;
    const bf16_t* vt_g = VT16 + (size_t)bh * Dd * Tt;   // [d][t]
    const bf16_t* p_g  = P16 + (size_t)bh * Tt * Dd;

    __shared__ __align__(16) char smem[38912];
    bf16_t (*pA)[72]  = (bf16_t (*)[72])(smem);           // 128 rows (P band)
    bf16_t (*k_s)[72] = (bf16_t (*)[72])(smem + 18432);   // 64 rows
    bf16_t (*msw)[88] = (bf16_t (*)[88])(smem + 27648);   // 64 rows, strip-local

    const int off_w = 48 - wave * 16;          // strip-local = absolute - off_w
    const int cmin = 48 - wave * 16;           // absolute strip window
    const int cmax = 126 - wave * 16;

    // A-operand fragments, direct global loads: A[m=l16][k=quad*8+e]
    const int qrow = i0 + wave * 16 + l16;
    const int qrow2 = (qrow + 1 > Tt - 1) ? (Tt - 1) : (qrow + 1);  // clamped row never gathered
    bf16x8 aq[2], av1[2], av2[2];
#pragma unroll
    for (int kc = 0; kc < 2; kc++) {
        aq[kc]  = *(const bf16x8*)(qu_g + (size_t)qrow  * Dd + kc * 32 + quad * 8);
        av1[kc] = *(const bf16x8*)(qv_g + (size_t)qrow  * Dd + kc * 32 + quad * 8);
        av2[kc] = *(const bf16x8*)(qv_g + (size_t)qrow2 * Dd + kc * 32 + quad * 8);
    }

    float lsum[4];
    f32x4 accO[4];
#pragma unroll
    for (int r = 0; r < 4; r++) lsum[r] = 0.f;
#pragma unroll
    for (int dt = 0; dt < 4; dt++)
#pragma unroll
        for (int r = 0; r < 4; r++) accO[dt][r] = 0.f;

    for (int j0 = 0; j0 < Tt; j0 += 64) {
        int d_lo = i0 - (j0 + 63);
        int d_hi = i0 + 63 - j0;
        int w1 = 0, prow1 = 0;
        if (d_hi >= 0) {
            int b1 = d_lo > 0 ? d_lo : 0;
            w1 = d_hi - b1 + 1;
            prow1 = (Tt - 1) - d_hi;
        }
        int dmax2 = d_hi < -2 ? d_hi : -2;
        int w2 = 0, e_lo = 0;
        if (d_lo <= dmax2) {
            e_lo = -dmax2 - 2;
            int e_hi = -d_lo - 2;
            w2 = e_hi - e_lo + 1;
        }
        int c2_0 = d_hi + 2 + e_lo;
        int nct1 = (w1 + 15) >> 4;
        int nct2 = (w2 + 15) >> 4;

        // stage K tile (coalesced; 2-way LDS writes = free)
        for (int idx = tid; idx < 64 * 8; idx += 256) {
            int row = idx >> 3, seg = idx & 7;
            *(f32x4*)&k_s[row][seg * 8] = *(const f32x4*)(k_g + (size_t)(j0 + row) * Dd + seg * 8);
        }
        // stage P band rows [0, w1+w2)
        for (int idx = tid; idx < (w1 + w2) * 8; idx += 256) {
            int rr = idx >> 3, seg = idx & 7;
            int srcrow = (rr < w1) ? (prow1 + rr) : (e_lo + rr - w1);
            *(f32x4*)&pA[rr][seg * 8] = *(const f32x4*)(p_g + (size_t)srcrow * Dd + seg * 8);
        }
        __syncthreads();

        // content scores
        f32x4 accS[4];
#pragma unroll
        for (int nt = 0; nt < 4; nt++) {
            f32x4 acc = {0.f, 0.f, 0.f, 0.f};
#pragma unroll
            for (int kc = 0; kc < 2; kc++) {
                bf16x8 bk8 = *(const bf16x8*)&k_s[nt * 16 + l16][kc * 32 + quad * 8];
                acc = __builtin_amdgcn_mfma_f32_16x16x32_bf16(aq[kc], bk8, acc, 0, 0, 0);
            }
            accS[nt] = acc;
        }

        // banded pos matmul -> strip-local skewed store (wave-private)
        for (int ct = 0; ct < nct1 + nct2; ct++) {
            bool b2 = ct >= nct1;
            int rb_ = b2 ? (w1 + (ct - nct1) * 16) : (ct * 16);
            int cb_ = b2 ? (c2_0 + (ct - nct1) * 16) : (ct * 16);
            if (cb_ > cmax || cb_ + 15 < cmin) continue;
            f32x4 acc = {0.f, 0.f, 0.f, 0.f};
#pragma unroll
            for (int kc = 0; kc < 2; kc++) {
                bf16x8 bp = *(const bf16x8*)&pA[rb_ + l16][kc * 32 + quad * 8];
                acc = b2 ? __builtin_amdgcn_mfma_f32_16x16x32_bf16(av2[kc], bp, acc, 0, 0, 0)
                         : __builtin_amdgcn_mfma_f32_16x16x32_bf16(av1[kc], bp, acc, 0, 0, 0);
            }
            int colp = cb_ + l16 - off_w;          // strip-local
            if ((unsigned)colp < 80u) {
#pragma unroll
                for (int r = 0; r < 4; r++)
                    msw[wave * 16 + quad * 4 + r][colp] = (bf16_t)acc[r];
            }
        }
        // zero column for dd == -1 (strip-local)
        {
            int zcl = d_hi + 1 - off_w;
            if ((unsigned)zcl < 80u && quad == 0)
                msw[wave * 16 + l16][zcl] = (bf16_t)0.f;
        }

        // gather all 16 (no aliasing stores in between), then write weights
        float wv[4][4];
#pragma unroll
        for (int nt = 0; nt < 4; nt++) {
#pragma unroll
            for (int r = 0; r < 4; r++) {
                float pos = (float)msw[wave * 16 + quad * 4 + r]
                                    [nt * 16 + l16 + 15 - (quad * 4 + r)];
                float x = accS[nt][r] + pos;
                float a = fminf(fmaf(x, 0.18033688f, -17.3123405f), 120.0f);
                float w = exp2f(a);
                lsum[r] += w;
                wv[nt][r] = w;
            }
        }
#pragma unroll
        for (int nt = 0; nt < 4; nt++)
#pragma unroll
            for (int r = 0; r < 4; r++)
                msw[wave * 16 + quad * 4 + r][nt * 16 + l16] = (bf16_t)wv[nt][r];

        // O += W @ V : A from own msw strip, B direct from VT ([d][t])
#pragma unroll
        for (int kc = 0; kc < 2; kc++) {
            bf16x8 aw = *(const bf16x8*)&msw[wave * 16 + l16][kc * 32 + quad * 8];
#pragma unroll
            for (int dt = 0; dt < 4; dt++) {
                bf16x8 bv8 = *(const bf16x8*)(vt_g + (size_t)(dt * 16 + l16) * Tt + j0 + kc * 32 + quad * 8);
                accO[dt] = __builtin_amdgcn_mfma_f32_16x16x32_bf16(aw, bv8, accO[dt], 0, 0, 0);
            }
        }
        __syncthreads();  // protect k_s/pA before next staging
    }

#pragma unroll
    for (int r = 0; r < 4; r++) {
#pragma unroll
        for (int off = 1; off < 16; off <<= 1) lsum[r] += __shfl_xor(lsum[r], off, 64);
    }

#pragma unroll
    for (int r = 0; r < 4; r++) {
        int il = wave * 16 + quad * 4 + r;
        int ig = i0 + il;
        float inv = 1.0f / lsum[r];
#pragma unroll
        for (int dt = 0; dt < 4; dt++) {
            CTX[((size_t)(b * Tt + ig)) * Cc + h * Dd + dt * 16 + l16] = accO[dt][r] * inv;
        }
    }
}

// ---------------------------------------------------------------------------
extern "C" void kernel_launch(void* const* d_in, const int* in_sizes, int n_in,
                              void* d_out, int out_size, void* d_ws, size_t ws_size,
                              hipStream_t stream)
{
    const float* query = (const float*)d_in[0];
    const float* key   = (const float*)d_in[1];
    const float* value = (const float*)d_in[2];
    const float* pemb  = (const float*)d_in[3];
    const float* Wq    = (const float*)d_in[4];
    const float* bq    = (const float*)d_in[5];
    const float* Wk    = (const float*)d_in[6];
    const float* bk    = (const float*)d_in[7];
    const float* Wv    = (const float*)d_in[8];
    const float* bv    = (const float*)d_in[9];
    const float* Wpos  = (const float*)d_in[10];
    const float* pbu   = (const float*)d_in[11];
    const float* pbv   = (const float*)d_in[12];
    const float* Wo    = (const float*)d_in[13];
    const float* bo    = (const float*)d_in[14];

    const size_t NE = (size_t)Bb * Hh * Tt * Dd;  // 4,194,304 per tensor
    bf16_t* QU   = (bf16_t*)d_ws;
    bf16_t* QV   = QU + NE;
    bf16_t* K16  = QV + NE;
    bf16_t* VT16 = K16 + NE;
    bf16_t* P16  = VT16 + NE;
    float*  CTX  = (float*)(P16 + NE);            // ws >= 56 MB (unchanged)

    // W^T hi/lo planes overlaid on dead regions (no extra workspace):
    //  - WT4 (Wq,Wk,Wv,Wpos; 4 MB) in CTX region: dead until attn writes CTX.
    //  - WoT (1 MB) in QU region: written AFTER attn (QU dead by then).
    bf16_t* WT4 = (bf16_t*)CTX;
    bf16_t* WoT = (bf16_t*)QU;

    // prepass A: Wq/Wk/Wv/Wpos -> transposed hi/lo bf16 planes
    wsplit_kernel<<<dim3(64, 4), 256, 0, stream>>>(Wq, Wk, Wv, Wpos, Wo, WT4, WoT, -1);

    // QKVP projections (z = blockIdx.z)
    split_gemm_kernel<<<dim3(256, 1, 4), 256, 0, stream>>>(
        query, key, value, pemb, CTX, WT4, WoT,
        bq, bk, bv, bo, pbu, pbv, QU, QV, K16, VT16, P16, (float*)d_out, -1);

    attn_kernel<<<dim3(32, 32), 256, 0, stream>>>(QU, QV, K16, VT16, P16, CTX);

    // prepass B: Wo -> WoT (QU region now dead)
    wsplit_kernel<<<dim3(64, 1), 256, 0, stream>>>(Wq, Wk, Wv, Wpos, Wo, WT4, WoT, 4);

    // output projection (mode 4)
    split_gemm_kernel<<<dim3(256, 1, 1), 256, 0, stream>>>(
        query, key, value, pemb, CTX, WT4, WoT,
        bq, bk, bv, bo, pbu, pbv, QU, QV, K16, VT16, P16, (float*)d_out, 4);
}

// Round 8
// 432.742 us; speedup vs baseline: 1.3891x; 1.1029x over previous
//
#include <hip/hip_runtime.h>

// ---------------------------------------------------------------------------
// RelPositionMultiHeadedAttention (Conformer / Transformer-XL rel-shift)
// B=4, T=2048, C=512, H=8, D=64
//
// R16: occupancy round (attn = R12-exact, verified 226-229us).
//  - QKVP split_gemm: BK 64->32. LDS 40960 B -> 3 blocks/CU @ lb(256,3)
//    (12 waves/CU vs 8); 16 K-iters, 48 MFMA each; same k-chunk order =>
//    bit-identical accumulation.
//  - out-proj: new 64x128-tile kernel, 512 blocks -> 2 blocks/CU (was 256
//    blocks = 1/CU, latency-naked).
// ---------------------------------------------------------------------------

#define Bb 4
#define Tt 2048
#define Cc 512
#define Hh 8
#define Dd 64

typedef __bf16 bf16_t;
typedef __bf16 bf16x8 __attribute__((ext_vector_type(8)));
typedef __bf16 bf16x4 __attribute__((ext_vector_type(4)));
typedef float  f32x4  __attribute__((ext_vector_type(4)));

// ---------------------------------------------------------------------------
// Prepass: WT_hi[n][k], WT_lo[n][k] bf16 from W[k][n] f32.
// ---------------------------------------------------------------------------
__global__ __launch_bounds__(256, 4)
void wsplit_kernel(const float* __restrict__ Wq, const float* __restrict__ Wk,
                   const float* __restrict__ Wv, const float* __restrict__ Wp,
                   const float* __restrict__ Wo,
                   bf16_t* __restrict__ WT4, bf16_t* __restrict__ WoT, int mode)
{
    const int w = (mode < 0) ? (int)blockIdx.y : 4;
    const float* W = (w == 0) ? Wq : (w == 1) ? Wk : (w == 2) ? Wv : (w == 3) ? Wp : Wo;
    bf16_t* dh = (w == 4) ? WoT : WT4 + (size_t)w * 2 * 262144;
    bf16_t* dl = dh + 262144;

    const int tile = blockIdx.x;           // 64 tiles of 64x64
    const int k0 = (tile >> 3) * 64;
    const int n0 = (tile & 7) * 64;
    const int tid = threadIdx.x;

    __shared__ bf16_t th[64][66];
    __shared__ bf16_t tl[64][66];

#pragma unroll
    for (int rep = 0; rep < 4; rep++) {
        int id = rep * 256 + tid;          // 1024 ids: 64 k-rows x 16 f32x4 segs
        int kk = id >> 4, ns = id & 15;
        f32x4 v = *(const f32x4*)&W[(size_t)(k0 + kk) * 512 + n0 + ns * 4];
#pragma unroll
        for (int e = 0; e < 4; e++) {
            bf16_t h = (bf16_t)v[e];
            th[kk][ns * 4 + e] = h;
            tl[kk][ns * 4 + e] = (bf16_t)(v[e] - (float)h);
        }
    }
    __syncthreads();
#pragma unroll
    for (int rep = 0; rep < 2; rep++) {
        int id = rep * 256 + tid;          // 512 ids: 64 n-rows x 8 k-segs
        int nn = id >> 3, ks = id & 7;
        bf16x8 hv, lv;
#pragma unroll
        for (int j = 0; j < 8; j++) { hv[j] = th[ks * 8 + j][nn]; lv[j] = tl[ks * 8 + j][nn]; }
        *(bf16x8*)&dh[(size_t)(n0 + nn) * 512 + k0 + ks * 8] = hv;
        *(bf16x8*)&dl[(size_t)(n0 + nn) * 512 + k0 + ks * 8] = lv;
    }
}

// ---------------------------------------------------------------------------
// QKVP split-bf16 GEMM, BK=32: Y = X @ W (+bias). X fp32 (converted at
// staging), W via prepass planes WT[n][k]. LDS 40960 B -> 3 blocks/CU.
// z = blockIdx.z: 0=Q(->QU,QV) 1=K 2=V(->VT) 3=P.
// ---------------------------------------------------------------------------
__global__ __launch_bounds__(256, 3)
void split_gemm_kernel(const float* __restrict__ Xq, const float* __restrict__ Xk,
                       const float* __restrict__ Xv, const float* __restrict__ Xp,
                       const bf16_t* __restrict__ WT4,
                       const float* __restrict__ bq, const float* __restrict__ bk,
                       const float* __restrict__ bv,
                       const float* __restrict__ bias_u, const float* __restrict__ bias_v,
                       bf16_t* __restrict__ QU, bf16_t* __restrict__ QV,
                       bf16_t* __restrict__ K16, bf16_t* __restrict__ VT16,
                       bf16_t* __restrict__ P16)
{
    const int z = blockIdx.z;
    const float* X    = (z == 0) ? Xq : (z == 1) ? Xk : (z == 2) ? Xv : Xp;
    const bf16_t* Wh  = WT4 + (size_t)z * 2 * 262144;
    const bf16_t* Wl  = Wh + 262144;
    const float* bias = (z == 0) ? bq : (z == 1) ? bk : (z == 2) ? bv : nullptr;

    const int bx = blockIdx.x;
    const int g  = bx >> 3, x8 = bx & 7;
    const int mtile = (g >> 2) * 8 + x8;   // 0..63
    const int ntile = g & 3;               // 0..3
    const int r0 = mtile * 128;
    const int c0 = ntile * 128;

    const int tid  = threadIdx.x;
    const int wave = tid >> 6;
    const int lane = tid & 63;
    const int quad = lane >> 4;
    const int l16  = lane & 15;
    const int rb = (wave >> 1) * 64;
    const int cb = (wave & 1) * 64;

    __shared__ __align__(16) bf16_t Ah[128][40];
    __shared__ __align__(16) bf16_t Al[128][40];
    __shared__ __align__(16) bf16_t Bh[128][40];
    __shared__ __align__(16) bf16_t Bl[128][40];

    f32x4 acc[4][4];
#pragma unroll
    for (int mt = 0; mt < 4; mt++)
#pragma unroll
        for (int nt = 0; nt < 4; nt++)
#pragma unroll
            for (int r = 0; r < 4; r++) acc[mt][nt][r] = 0.f;

    // staged-tile registers (BK=32)
    f32x4  xa[4];
    bf16x8 wbh[2], wbl[2];

    // prologue: K-chunk 0
#pragma unroll
    for (int rep = 0; rep < 4; rep++) {
        int id = rep * 256 + tid;          // 1024 ids: 128 rows x 8 f32x4 segs
        int m = id >> 3, c = id & 7;
        xa[rep] = *(const f32x4*)&X[(size_t)(r0 + m) * 512 + c * 4];
    }
#pragma unroll
    for (int rep = 0; rep < 2; rep++) {
        int id = rep * 256 + tid;          // 512 ids: 128 rows x 4 k-segs
        int n = id >> 2, seg = id & 3;
        wbh[rep] = *(const bf16x8*)&Wh[(size_t)(c0 + n) * 512 + seg * 8];
        wbl[rep] = *(const bf16x8*)&Wl[(size_t)(c0 + n) * 512 + seg * 8];
    }

    for (int it = 0; it < 16; ++it) {
        // write staged regs to LDS (hi/lo conversion once per element)
#pragma unroll
        for (int rep = 0; rep < 4; rep++) {
            int id = rep * 256 + tid;
            int m = id >> 3, c = id & 7;
            f32x4 v = xa[rep];
            bf16x4 hh, ll;
#pragma unroll
            for (int e = 0; e < 4; e++) {
                bf16_t hv = (bf16_t)v[e];
                hh[e] = hv;
                ll[e] = (bf16_t)(v[e] - (float)hv);
            }
            *(bf16x4*)&Ah[m][c * 4] = hh;
            *(bf16x4*)&Al[m][c * 4] = ll;
        }
#pragma unroll
        for (int rep = 0; rep < 2; rep++) {
            int id = rep * 256 + tid;
            int n = id >> 2, seg = id & 3;
            *(bf16x8*)&Bh[n][seg * 8] = wbh[rep];
            *(bf16x8*)&Bl[n][seg * 8] = wbl[rep];
        }
        __syncthreads();

        // prefetch next K-chunk into regs (in flight under the MFMAs below)
        if (it < 15) {
            const int k0n = (it + 1) * 32;
#pragma unroll
            for (int rep = 0; rep < 4; rep++) {
                int id = rep * 256 + tid;
                int m = id >> 3, c = id & 7;
                xa[rep] = *(const f32x4*)&X[(size_t)(r0 + m) * 512 + k0n + c * 4];
            }
#pragma unroll
            for (int rep = 0; rep < 2; rep++) {
                int id = rep * 256 + tid;
                int n = id >> 2, seg = id & 3;
                wbh[rep] = *(const bf16x8*)&Wh[(size_t)(c0 + n) * 512 + k0n + seg * 8];
                wbl[rep] = *(const bf16x8*)&Wl[(size_t)(c0 + n) * 512 + k0n + seg * 8];
            }
        }

        // compute on LDS tile (single 32-wide K chunk)
        {
            bf16x8 bh[4], bl[4], ah[4], al[4];
#pragma unroll
            for (int nt = 0; nt < 4; nt++) {
                bh[nt] = *(const bf16x8*)&Bh[cb + nt * 16 + l16][quad * 8];
                bl[nt] = *(const bf16x8*)&Bl[cb + nt * 16 + l16][quad * 8];
            }
#pragma unroll
            for (int mt = 0; mt < 4; mt++) {
                ah[mt] = *(const bf16x8*)&Ah[rb + mt * 16 + l16][quad * 8];
                al[mt] = *(const bf16x8*)&Al[rb + mt * 16 + l16][quad * 8];
            }
#pragma unroll
            for (int mt = 0; mt < 4; mt++) {
#pragma unroll
                for (int nt = 0; nt < 4; nt++) {
                    acc[mt][nt] = __builtin_amdgcn_mfma_f32_16x16x32_bf16(ah[mt], bh[nt], acc[mt][nt], 0, 0, 0);
                    acc[mt][nt] = __builtin_amdgcn_mfma_f32_16x16x32_bf16(ah[mt], bl[nt], acc[mt][nt], 0, 0, 0);
                    acc[mt][nt] = __builtin_amdgcn_mfma_f32_16x16x32_bf16(al[mt], bh[nt], acc[mt][nt], 0, 0, 0);
                }
            }
        }
        __syncthreads();
    }

#pragma unroll
    for (int mt = 0; mt < 4; mt++) {
#pragma unroll
        for (int r = 0; r < 4; r++) {
            int row = r0 + rb + mt * 16 + quad * 4 + r;
#pragma unroll
            for (int nt = 0; nt < 4; nt++) {
                int col = c0 + cb + nt * 16 + l16;
                float y = acc[mt][nt][r] + (bias ? bias[col] : 0.f);
                int b = row >> 11, t = row & 2047;
                int h = col >> 6,  d = col & 63;
                if (z == 0) {
                    size_t idx = (((size_t)(b * Hh + h)) * Tt + t) * Dd + d;
                    QU[idx] = (bf16_t)(y + bias_u[col]);
                    QV[idx] = (bf16_t)(y + bias_v[col]);
                } else if (z == 1) {
                    size_t idx = (((size_t)(b * Hh + h)) * Tt + t) * Dd + d;
                    K16[idx] = (bf16_t)y;
                } else if (z == 2) {
                    // transposed: VT[bh][d][t]
                    size_t idx = (((size_t)(b * Hh + h)) * Dd + d) * Tt + t;
                    VT16[idx] = (bf16_t)y;
                } else {
                    size_t idx = (((size_t)(b * Hh + h)) * Tt + t) * Dd + d;
                    P16[idx] = (bf16_t)y;
                }
            }
        }
    }
}

// ---------------------------------------------------------------------------
// Out-projection GEMM: OUT = CTX @ Wo + bo. 64x128 tiles -> 512 blocks
// (2 blocks/CU). BK=64, R12-style reg-prefetch. LDS 55296 B.
// ---------------------------------------------------------------------------
__global__ __launch_bounds__(256, 2)
void out_gemm_kernel(const float* __restrict__ Xc, const bf16_t* __restrict__ WoT,
                     const float* __restrict__ bo, float* __restrict__ OUT)
{
    const bf16_t* Wh = WoT;
    const bf16_t* Wl = WoT + 262144;

    const int bx = blockIdx.x;             // 512 blocks: 128 mtiles x 4 ntiles
    const int r0 = (bx >> 2) * 64;
    const int c0 = (bx & 3) * 128;

    const int tid  = threadIdx.x;
    const int wave = tid >> 6;
    const int lane = tid & 63;
    const int quad = lane >> 4;
    const int l16  = lane & 15;
    const int rb = (wave >> 1) * 32;
    const int cb = (wave & 1) * 64;

    __shared__ __align__(16) bf16_t Ah[64][72];
    __shared__ __align__(16) bf16_t Al[64][72];
    __shared__ __align__(16) bf16_t Bh[128][72];
    __shared__ __align__(16) bf16_t Bl[128][72];

    f32x4 acc[2][4];
#pragma unroll
    for (int mt = 0; mt < 2; mt++)
#pragma unroll
        for (int nt = 0; nt < 4; nt++)
#pragma unroll
            for (int r = 0; r < 4; r++) acc[mt][nt][r] = 0.f;

    f32x4  xa[4];
    bf16x8 wbh[4], wbl[4];

    // prologue: K-step 0
#pragma unroll
    for (int rep = 0; rep < 4; rep++) {
        int id = rep * 256 + tid;          // 1024 ids: 64 rows x 16 f32x4 segs
        int m = id >> 4, c = id & 15;
        xa[rep] = *(const f32x4*)&Xc[(size_t)(r0 + m) * 512 + c * 4];
    }
#pragma unroll
    for (int rep = 0; rep < 4; rep++) {
        int id = rep * 256 + tid;          // 1024 ids: 128 rows x 8 k-segs
        int n = id >> 3, seg = id & 7;
        wbh[rep] = *(const bf16x8*)&Wh[(size_t)(c0 + n) * 512 + seg * 8];
        wbl[rep] = *(const bf16x8*)&Wl[(size_t)(c0 + n) * 512 + seg * 8];
    }

    for (int it = 0; it < 8; ++it) {
#pragma unroll
        for (int rep = 0; rep < 4; rep++) {
            int id = rep * 256 + tid;
            int m = id >> 4, c = id & 15;
            f32x4 v = xa[rep];
            bf16x4 hh, ll;
#pragma unroll
            for (int e = 0; e < 4; e++) {
                bf16_t hv = (bf16_t)v[e];
                hh[e] = hv;
                ll[e] = (bf16_t)(v[e] - (float)hv);
            }
            *(bf16x4*)&Ah[m][c * 4] = hh;
            *(bf16x4*)&Al[m][c * 4] = ll;
        }
#pragma unroll
        for (int rep = 0; rep < 4; rep++) {
            int id = rep * 256 + tid;
            int n = id >> 3, seg = id & 7;
            *(bf16x8*)&Bh[n][seg * 8] = wbh[rep];
            *(bf16x8*)&Bl[n][seg * 8] = wbl[rep];
        }
        __syncthreads();

        if (it < 7) {
            const int k0n = (it + 1) * 64;
#pragma unroll
            for (int rep = 0; rep < 4; rep++) {
                int id = rep * 256 + tid;
                int m = id >> 4, c = id & 15;
                xa[rep] = *(const f32x4*)&Xc[(size_t)(r0 + m) * 512 + k0n + c * 4];
            }
#pragma unroll
            for (int rep = 0; rep < 4; rep++) {
                int id = rep * 256 + tid;
                int n = id >> 3, seg = id & 7;
                wbh[rep] = *(const bf16x8*)&Wh[(size_t)(c0 + n) * 512 + k0n + seg * 8];
                wbl[rep] = *(const bf16x8*)&Wl[(size_t)(c0 + n) * 512 + k0n + seg * 8];
            }
        }

#pragma unroll
        for (int kc = 0; kc < 2; kc++) {
            bf16x8 bh[4], bl[4], ah[2], al[2];
#pragma unroll
            for (int nt = 0; nt < 4; nt++) {
                bh[nt] = *(const bf16x8*)&Bh[cb + nt * 16 + l16][kc * 32 + quad * 8];
                bl[nt] = *(const bf16x8*)&Bl[cb + nt * 16 + l16][kc * 32 + quad * 8];
            }
#pragma unroll
            for (int mt = 0; mt < 2; mt++) {
                ah[mt] = *(const bf16x8*)&Ah[rb + mt * 16 + l16][kc * 32 + quad * 8];
                al[mt] = *(const bf16x8*)&Al[rb + mt * 16 + l16][kc * 32 + quad * 8];
            }
#pragma unroll
            for (int mt = 0; mt < 2; mt++) {
#pragma unroll
                for (int nt = 0; nt < 4; nt++) {
                    acc[mt][nt] = __builtin_amdgcn_mfma_f32_16x16x32_bf16(ah[mt], bh[nt], acc[mt][nt], 0, 0, 0);
                    acc[mt][nt] = __builtin_amdgcn_mfma_f32_16x16x32_bf16(ah[mt], bl[nt], acc[mt][nt], 0, 0, 0);
                    acc[mt][nt] = __builtin_amdgcn_mfma_f32_16x16x32_bf16(al[mt], bh[nt], acc[mt][nt], 0, 0, 0);
                }
            }
        }
        __syncthreads();
    }

#pragma unroll
    for (int mt = 0; mt < 2; mt++) {
#pragma unroll
        for (int r = 0; r < 4; r++) {
            int row = r0 + rb + mt * 16 + quad * 4 + r;
#pragma unroll
            for (int nt = 0; nt < 4; nt++) {
                int col = c0 + cb + nt * 16 + l16;
                OUT[(size_t)row * 512 + col] = acc[mt][nt][r] + bo[col];
            }
        }
    }
}

// ---------------------------------------------------------------------------
// Kernel 2: attention (R12-exact, verified 226-229us). grid = (bh=32, it=32).
// LDS map (bytes), total 38912:
//   [0,     18432)  pA  [128][72] bf16: P band rows 0..(w1+w2)
//   [18432, 27648)  k_s [64][72]
//   [27648, 38912)  msw [64][88] bf16, wave-private strips, STRIP-LOCAL
//                   skewed pos scores; softmax weights later clobber cols
//                   0..63 (strictly after the gathers).
// ---------------------------------------------------------------------------
__global__ __launch_bounds__(256, 3)
void attn_kernel(const bf16_t* __restrict__ QU, const bf16_t* __restrict__ QV,
                 const bf16_t* __restrict__ K16, const bf16_t* __restrict__ VT16,
                 const bf16_t* __restrict__ P16, float* __restrict__ CTX)
{
    const int bh = blockIdx.x;                 // XCD locality: linear%8 = bh%8
    const int i0 = blockIdx.y * 64;
    const int b = bh >> 3, h = bh & 7;
    const int tid = threadIdx.x;
    const int wave = tid >> 6;
    const int lane = tid & 63;
    const int quad = lane >> 4;
    const int l16 = lane & 15;

    const bf16_t* qu_g = QU + (size_t)bh * Tt * Dd;
    const bf16_t* qv_g = QV + (size_t)bh * Tt * Dd;
    const bf16_t* k_g  = K16 + (size_t)bh * Tt * Dd;
    const bf16_t* vt_g = VT16 + (size_t)bh * Dd * Tt;   // [d][t]
    const bf16_t* p_g  = P16 + (size_t)bh * Tt * Dd;

    __shared__ __align__(16) char smem[38912];
    bf16_t (*pA)[72]  = (bf16_t (*)[72])(smem);           // 128 rows (P band)
    bf16_t (*k_s)[72] = (bf16_t (*)[72])(smem + 18432);   // 64 rows
    bf16_t (*msw)[88] = (bf16_t (*)[88])(smem + 27648);   // 64 rows, strip-local

    const int off_w = 48 - wave * 16;          // strip-local = absolute - off_w
    const int cmin = 48 - wave * 16;           // absolute strip window
    const int cmax = 126 - wave * 16;

    // A-operand fragments, direct global loads: A[m=l16][k=quad*8+e]
    const int qrow = i0 + wave * 16 + l16;
    const int qrow2 = (qrow + 1 > Tt - 1) ? (Tt - 1) : (qrow + 1);  // clamped row never gathered
    bf16x8 aq[2], av1[2], av2[2];
#pragma unroll
    for (int kc = 0; kc < 2; kc++) {
        aq[kc]  = *(const bf16x8*)(qu_g + (size_t)qrow  * Dd + kc * 32 + quad * 8);
        av1[kc] = *(const bf16x8*)(qv_g + (size_t)qrow  * Dd + kc * 32 + quad * 8);
        av2[kc] = *(const bf16x8*)(qv_g + (size_t)qrow2 * Dd + kc * 32 + quad * 8);
    }

    float lsum[4];
    f32x4 accO[4];
#pragma unroll
    for (int r = 0; r < 4; r++) lsum[r] = 0.f;
#pragma unroll
    for (int dt = 0; dt < 4; dt++)
#pragma unroll
        for (int r = 0; r < 4; r++) accO[dt][r] = 0.f;

    for (int j0 = 0; j0 < Tt; j0 += 64) {
        int d_lo = i0 - (j0 + 63);
        int d_hi = i0 + 63 - j0;
        int w1 = 0, prow1 = 0;
        if (d_hi >= 0) {
            int b1 = d_lo > 0 ? d_lo : 0;
            w1 = d_hi - b1 + 1;
            prow1 = (Tt - 1) - d_hi;
        }
        int dmax2 = d_hi < -2 ? d_hi : -2;
        int w2 = 0, e_lo = 0;
        if (d_lo <= dmax2) {
            e_lo = -dmax2 - 2;
            int e_hi = -d_lo - 2;
            w2 = e_hi - e_lo + 1;
        }
        int c2_0 = d_hi + 2 + e_lo;
        int nct1 = (w1 + 15) >> 4;
        int nct2 = (w2 + 15) >> 4;

        // stage K tile (coalesced; 2-way LDS writes = free)
        for (int idx = tid; idx < 64 * 8; idx += 256) {
            int row = idx >> 3, seg = idx & 7;
            *(f32x4*)&k_s[row][seg * 8] = *(const f32x4*)(k_g + (size_t)(j0 + row) * Dd + seg * 8);
        }
        // stage P band rows [0, w1+w2)
        for (int idx = tid; idx < (w1 + w2) * 8; idx += 256) {
            int rr = idx >> 3, seg = idx & 7;
            int srcrow = (rr < w1) ? (prow1 + rr) : (e_lo + rr - w1);
            *(f32x4*)&pA[rr][seg * 8] = *(const f32x4*)(p_g + (size_t)srcrow * Dd + seg * 8);
        }
        __syncthreads();

        // content scores
        f32x4 accS[4];
#pragma unroll
        for (int nt = 0; nt < 4; nt++) {
            f32x4 acc = {0.f, 0.f, 0.f, 0.f};
#pragma unroll
            for (int kc = 0; kc < 2; kc++) {
                bf16x8 bk8 = *(const bf16x8*)&k_s[nt * 16 + l16][kc * 32 + quad * 8];
                acc = __builtin_amdgcn_mfma_f32_16x16x32_bf16(aq[kc], bk8, acc, 0, 0, 0);
            }
            accS[nt] = acc;
        }

        // banded pos matmul -> strip-local skewed store (wave-private)
        for (int ct = 0; ct < nct1 + nct2; ct++) {
            bool b2 = ct >= nct1;
            int rb_ = b2 ? (w1 + (ct - nct1) * 16) : (ct * 16);
            int cb_ = b2 ? (c2_0 + (ct - nct1) * 16) : (ct * 16);
            if (cb_ > cmax || cb_ + 15 < cmin) continue;
            f32x4 acc = {0.f, 0.f, 0.f, 0.f};
#pragma unroll
            for (int kc = 0; kc < 2; kc++) {
                bf16x8 bp = *(const bf16x8*)&pA[rb_ + l16][kc * 32 + quad * 8];
                acc = b2 ? __builtin_amdgcn_mfma_f32_16x16x32_bf16(av2[kc], bp, acc, 0, 0, 0)
                         : __builtin_amdgcn_mfma_f32_16x16x32_bf16(av1[kc], bp, acc, 0, 0, 0);
            }
            int colp = cb_ + l16 - off_w;          // strip-local
            if ((unsigned)colp < 80u) {
#pragma unroll
                for (int r = 0; r < 4; r++)
                    msw[wave * 16 + quad * 4 + r][colp] = (bf16_t)acc[r];
            }
        }
        // zero column for dd == -1 (strip-local)
        {
            int zcl = d_hi + 1 - off_w;
            if ((unsigned)zcl < 80u && quad == 0)
                msw[wave * 16 + l16][zcl] = (bf16_t)0.f;
        }

        // gather all 16 (no aliasing stores in between), then write weights
        float wv[4][4];
#pragma unroll
        for (int nt = 0; nt < 4; nt++) {
#pragma unroll
            for (int r = 0; r < 4; r++) {
                float pos = (float)msw[wave * 16 + quad * 4 + r]
                                    [nt * 16 + l16 + 15 - (quad * 4 + r)];
                float x = accS[nt][r] + pos;
                float a = fminf(fmaf(x, 0.18033688f, -17.3123405f), 120.0f);
                float w = exp2f(a);
                lsum[r] += w;
                wv[nt][r] = w;
            }
        }
#pragma unroll
        for (int nt = 0; nt < 4; nt++)
#pragma unroll
            for (int r = 0; r < 4; r++)
                msw[wave * 16 + quad * 4 + r][nt * 16 + l16] = (bf16_t)wv[nt][r];

        // O += W @ V : A from own msw strip, B direct from VT ([d][t])
#pragma unroll
        for (int kc = 0; kc < 2; kc++) {
            bf16x8 aw = *(const bf16x8*)&msw[wave * 16 + l16][kc * 32 + quad * 8];
#pragma unroll
            for (int dt = 0; dt < 4; dt++) {
                bf16x8 bv8 = *(const bf16x8*)(vt_g + (size_t)(dt * 16 + l16) * Tt + j0 + kc * 32 + quad * 8);
                accO[dt] = __builtin_amdgcn_mfma_f32_16x16x32_bf16(aw, bv8, accO[dt], 0, 0, 0);
            }
        }
        __syncthreads();  // protect k_s/pA before next staging
    }

#pragma unroll
    for (int r = 0; r < 4; r++) {
#pragma unroll
        for (int off = 1; off < 16; off <<= 1) lsum[r] += __shfl_xor(lsum[r], off, 64);
    }

#pragma unroll
    for (int r = 0; r < 4; r++) {
        int il = wave * 16 + quad * 4 + r;
        int ig = i0 + il;
        float inv = 1.0f / lsum[r];
#pragma unroll
        for (int dt = 0; dt < 4; dt++) {
            CTX[((size_t)(b * Tt + ig)) * Cc + h * Dd + dt * 16 + l16] = accO[dt][r] * inv;
        }
    }
}

// ---------------------------------------------------------------------------
extern "C" void kernel_launch(void* const* d_in, const int* in_sizes, int n_in,
                              void* d_out, int out_size, void* d_ws, size_t ws_size,
                              hipStream_t stream)
{
    const float* query = (const float*)d_in[0];
    const float* key   = (const float*)d_in[1];
    const float* value = (const float*)d_in[2];
    const float* pemb  = (const float*)d_in[3];
    const float* Wq    = (const float*)d_in[4];
    const float* bq    = (const float*)d_in[5];
    const float* Wk    = (const float*)d_in[6];
    const float* bk    = (const float*)d_in[7];
    const float* Wv    = (const float*)d_in[8];
    const float* bv    = (const float*)d_in[9];
    const float* Wpos  = (const float*)d_in[10];
    const float* pbu   = (const float*)d_in[11];
    const float* pbv   = (const float*)d_in[12];
    const float* Wo    = (const float*)d_in[13];
    const float* bo    = (const float*)d_in[14];

    const size_t NE = (size_t)Bb * Hh * Tt * Dd;  // 4,194,304 per tensor
    bf16_t* QU   = (bf16_t*)d_ws;
    bf16_t* QV   = QU + NE;
    bf16_t* K16  = QV + NE;
    bf16_t* VT16 = K16 + NE;
    bf16_t* P16  = VT16 + NE;
    float*  CTX  = (float*)(P16 + NE);            // ws >= 56 MB (unchanged)

    // W^T hi/lo planes overlaid on dead regions (no extra workspace):
    //  - WT4 (Wq,Wk,Wv,Wpos; 4 MB) in CTX region: dead until attn writes CTX.
    //  - WoT (1 MB) in QU region: written AFTER attn (QU dead by then).
    bf16_t* WT4 = (bf16_t*)CTX;
    bf16_t* WoT = (bf16_t*)QU;

    // prepass A: Wq/Wk/Wv/Wpos -> transposed hi/lo bf16 planes
    wsplit_kernel<<<dim3(64, 4), 256, 0, stream>>>(Wq, Wk, Wv, Wpos, Wo, WT4, WoT, -1);

    // QKVP projections (z = blockIdx.z)
    split_gemm_kernel<<<dim3(256, 1, 4), 256, 0, stream>>>(
        query, key, value, pemb, WT4,
        bq, bk, bv, pbu, pbv, QU, QV, K16, VT16, P16);

    attn_kernel<<<dim3(32, 32), 256, 0, stream>>>(QU, QV, K16, VT16, P16, CTX);

    // prepass B: Wo -> WoT (QU region now dead)
    wsplit_kernel<<<dim3(64, 1), 256, 0, stream>>>(Wq, Wk, Wv, Wpos, Wo, WT4, WoT, 4);

    // output projection: 64x128 tiles, 512 blocks
    out_gemm_kernel<<<dim3(512), 256, 0, stream>>>(CTX, WoT, bo, (float*)d_out);
}

// Round 9
// 410.410 us; speedup vs baseline: 1.4646x; 1.0544x over previous
//
#include <hip/hip_runtime.h>

// ---------------------------------------------------------------------------
// RelPositionMultiHeadedAttention (Conformer / Transformer-XL rel-shift)
// B=4, T=2048, C=512, H=8, D=64
//
// R17: attn T14 async-stage split (GEMM/prepass/out-proj = R16-exact).
//  - K/P global loads for tile j+1 issue into NAMED registers right after the
//    post-write barrier; they stay in flight under tile j's ~1500-cyc compute;
//    next iteration writes them to LDS. Same addresses/values/guards =>
//    bit-identical LDS contents. Removes the ~300-500 cyc exposed L2 latency
//    between the two barriers.
//  - lb(256,4): VGPR cap 128 (est ~100), preserves 4 blocks/CU.
// ---------------------------------------------------------------------------

#define Bb 4
#define Tt 2048
#define Cc 512
#define Hh 8
#define Dd 64

typedef __bf16 bf16_t;
typedef __bf16 bf16x8 __attribute__((ext_vector_type(8)));
typedef __bf16 bf16x4 __attribute__((ext_vector_type(4)));
typedef float  f32x4  __attribute__((ext_vector_type(4)));

// ---------------------------------------------------------------------------
// Prepass: WT_hi[n][k], WT_lo[n][k] bf16 from W[k][n] f32.
// ---------------------------------------------------------------------------
__global__ __launch_bounds__(256, 4)
void wsplit_kernel(const float* __restrict__ Wq, const float* __restrict__ Wk,
                   const float* __restrict__ Wv, const float* __restrict__ Wp,
                   const float* __restrict__ Wo,
                   bf16_t* __restrict__ WT4, bf16_t* __restrict__ WoT, int mode)
{
    const int w = (mode < 0) ? (int)blockIdx.y : 4;
    const float* W = (w == 0) ? Wq : (w == 1) ? Wk : (w == 2) ? Wv : (w == 3) ? Wp : Wo;
    bf16_t* dh = (w == 4) ? WoT : WT4 + (size_t)w * 2 * 262144;
    bf16_t* dl = dh + 262144;

    const int tile = blockIdx.x;           // 64 tiles of 64x64
    const int k0 = (tile >> 3) * 64;
    const int n0 = (tile & 7) * 64;
    const int tid = threadIdx.x;

    __shared__ bf16_t th[64][66];
    __shared__ bf16_t tl[64][66];

#pragma unroll
    for (int rep = 0; rep < 4; rep++) {
        int id = rep * 256 + tid;          // 1024 ids: 64 k-rows x 16 f32x4 segs
        int kk = id >> 4, ns = id & 15;
        f32x4 v = *(const f32x4*)&W[(size_t)(k0 + kk) * 512 + n0 + ns * 4];
#pragma unroll
        for (int e = 0; e < 4; e++) {
            bf16_t h = (bf16_t)v[e];
            th[kk][ns * 4 + e] = h;
            tl[kk][ns * 4 + e] = (bf16_t)(v[e] - (float)h);
        }
    }
    __syncthreads();
#pragma unroll
    for (int rep = 0; rep < 2; rep++) {
        int id = rep * 256 + tid;          // 512 ids: 64 n-rows x 8 k-segs
        int nn = id >> 3, ks = id & 7;
        bf16x8 hv, lv;
#pragma unroll
        for (int j = 0; j < 8; j++) { hv[j] = th[ks * 8 + j][nn]; lv[j] = tl[ks * 8 + j][nn]; }
        *(bf16x8*)&dh[(size_t)(n0 + nn) * 512 + k0 + ks * 8] = hv;
        *(bf16x8*)&dl[(size_t)(n0 + nn) * 512 + k0 + ks * 8] = lv;
    }
}

// ---------------------------------------------------------------------------
// QKVP split-bf16 GEMM, BK=32 (R16-exact).
// ---------------------------------------------------------------------------
__global__ __launch_bounds__(256, 3)
void split_gemm_kernel(const float* __restrict__ Xq, const float* __restrict__ Xk,
                       const float* __restrict__ Xv, const float* __restrict__ Xp,
                       const bf16_t* __restrict__ WT4,
                       const float* __restrict__ bq, const float* __restrict__ bk,
                       const float* __restrict__ bv,
                       const float* __restrict__ bias_u, const float* __restrict__ bias_v,
                       bf16_t* __restrict__ QU, bf16_t* __restrict__ QV,
                       bf16_t* __restrict__ K16, bf16_t* __restrict__ VT16,
                       bf16_t* __restrict__ P16)
{
    const int z = blockIdx.z;
    const float* X    = (z == 0) ? Xq : (z == 1) ? Xk : (z == 2) ? Xv : Xp;
    const bf16_t* Wh  = WT4 + (size_t)z * 2 * 262144;
    const bf16_t* Wl  = Wh + 262144;
    const float* bias = (z == 0) ? bq : (z == 1) ? bk : (z == 2) ? bv : nullptr;

    const int bx = blockIdx.x;
    const int g  = bx >> 3, x8 = bx & 7;
    const int mtile = (g >> 2) * 8 + x8;   // 0..63
    const int ntile = g & 3;               // 0..3
    const int r0 = mtile * 128;
    const int c0 = ntile * 128;

    const int tid  = threadIdx.x;
    const int wave = tid >> 6;
    const int lane = tid & 63;
    const int quad = lane >> 4;
    const int l16  = lane & 15;
    const int rb = (wave >> 1) * 64;
    const int cb = (wave & 1) * 64;

    __shared__ __align__(16) bf16_t Ah[128][40];
    __shared__ __align__(16) bf16_t Al[128][40];
    __shared__ __align__(16) bf16_t Bh[128][40];
    __shared__ __align__(16) bf16_t Bl[128][40];

    f32x4 acc[4][4];
#pragma unroll
    for (int mt = 0; mt < 4; mt++)
#pragma unroll
        for (int nt = 0; nt < 4; nt++)
#pragma unroll
            for (int r = 0; r < 4; r++) acc[mt][nt][r] = 0.f;

    // staged-tile registers (BK=32)
    f32x4  xa[4];
    bf16x8 wbh[2], wbl[2];

    // prologue: K-chunk 0
#pragma unroll
    for (int rep = 0; rep < 4; rep++) {
        int id = rep * 256 + tid;          // 1024 ids: 128 rows x 8 f32x4 segs
        int m = id >> 3, c = id & 7;
        xa[rep] = *(const f32x4*)&X[(size_t)(r0 + m) * 512 + c * 4];
    }
#pragma unroll
    for (int rep = 0; rep < 2; rep++) {
        int id = rep * 256 + tid;          // 512 ids: 128 rows x 4 k-segs
        int n = id >> 2, seg = id & 3;
        wbh[rep] = *(const bf16x8*)&Wh[(size_t)(c0 + n) * 512 + seg * 8];
        wbl[rep] = *(const bf16x8*)&Wl[(size_t)(c0 + n) * 512 + seg * 8];
    }

    for (int it = 0; it < 16; ++it) {
        // write staged regs to LDS (hi/lo conversion once per element)
#pragma unroll
        for (int rep = 0; rep < 4; rep++) {
            int id = rep * 256 + tid;
            int m = id >> 3, c = id & 7;
            f32x4 v = xa[rep];
            bf16x4 hh, ll;
#pragma unroll
            for (int e = 0; e < 4; e++) {
                bf16_t hv = (bf16_t)v[e];
                hh[e] = hv;
                ll[e] = (bf16_t)(v[e] - (float)hv);
            }
            *(bf16x4*)&Ah[m][c * 4] = hh;
            *(bf16x4*)&Al[m][c * 4] = ll;
        }
#pragma unroll
        for (int rep = 0; rep < 2; rep++) {
            int id = rep * 256 + tid;
            int n = id >> 2, seg = id & 3;
            *(bf16x8*)&Bh[n][seg * 8] = wbh[rep];
            *(bf16x8*)&Bl[n][seg * 8] = wbl[rep];
        }
        __syncthreads();

        // prefetch next K-chunk into regs (in flight under the MFMAs below)
        if (it < 15) {
            const int k0n = (it + 1) * 32;
#pragma unroll
            for (int rep = 0; rep < 4; rep++) {
                int id = rep * 256 + tid;
                int m = id >> 3, c = id & 7;
                xa[rep] = *(const f32x4*)&X[(size_t)(r0 + m) * 512 + k0n + c * 4];
            }
#pragma unroll
            for (int rep = 0; rep < 2; rep++) {
                int id = rep * 256 + tid;
                int n = id >> 2, seg = id & 3;
                wbh[rep] = *(const bf16x8*)&Wh[(size_t)(c0 + n) * 512 + k0n + seg * 8];
                wbl[rep] = *(const bf16x8*)&Wl[(size_t)(c0 + n) * 512 + k0n + seg * 8];
            }
        }

        // compute on LDS tile (single 32-wide K chunk)
        {
            bf16x8 bh[4], bl[4], ah[4], al[4];
#pragma unroll
            for (int nt = 0; nt < 4; nt++) {
                bh[nt] = *(const bf16x8*)&Bh[cb + nt * 16 + l16][quad * 8];
                bl[nt] = *(const bf16x8*)&Bl[cb + nt * 16 + l16][quad * 8];
            }
#pragma unroll
            for (int mt = 0; mt < 4; mt++) {
                ah[mt] = *(const bf16x8*)&Ah[rb + mt * 16 + l16][quad * 8];
                al[mt] = *(const bf16x8*)&Al[rb + mt * 16 + l16][quad * 8];
            }
#pragma unroll
            for (int mt = 0; mt < 4; mt++) {
#pragma unroll
                for (int nt = 0; nt < 4; nt++) {
                    acc[mt][nt] = __builtin_amdgcn_mfma_f32_16x16x32_bf16(ah[mt], bh[nt], acc[mt][nt], 0, 0, 0);
                    acc[mt][nt] = __builtin_amdgcn_mfma_f32_16x16x32_bf16(ah[mt], bl[nt], acc[mt][nt], 0, 0, 0);
                    acc[mt][nt] = __builtin_amdgcn_mfma_f32_16x16x32_bf16(al[mt], bh[nt], acc[mt][nt], 0, 0, 0);
                }
            }
        }
        __syncthreads();
    }

#pragma unroll
    for (int mt = 0; mt < 4; mt++) {
#pragma unroll
        for (int r = 0; r < 4; r++) {
            int row = r0 + rb + mt * 16 + quad * 4 + r;
#pragma unroll
            for (int nt = 0; nt < 4; nt++) {
                int col = c0 + cb + nt * 16 + l16;
                float y = acc[mt][nt][r] + (bias ? bias[col] : 0.f);
                int b = row >> 11, t = row & 2047;
                int h = col >> 6,  d = col & 63;
                if (z == 0) {
                    size_t idx = (((size_t)(b * Hh + h)) * Tt + t) * Dd + d;
                    QU[idx] = (bf16_t)(y + bias_u[col]);
                    QV[idx] = (bf16_t)(y + bias_v[col]);
                } else if (z == 1) {
                    size_t idx = (((size_t)(b * Hh + h)) * Tt + t) * Dd + d;
                    K16[idx] = (bf16_t)y;
                } else if (z == 2) {
                    // transposed: VT[bh][d][t]
                    size_t idx = (((size_t)(b * Hh + h)) * Dd + d) * Tt + t;
                    VT16[idx] = (bf16_t)y;
                } else {
                    size_t idx = (((size_t)(b * Hh + h)) * Tt + t) * Dd + d;
                    P16[idx] = (bf16_t)y;
                }
            }
        }
    }
}

// ---------------------------------------------------------------------------
// Out-projection GEMM (R16-exact): OUT = CTX @ Wo + bo. 64x128 tiles.
// ---------------------------------------------------------------------------
__global__ __launch_bounds__(256, 2)
void out_gemm_kernel(const float* __restrict__ Xc, const bf16_t* __restrict__ WoT,
                     const float* __restrict__ bo, float* __restrict__ OUT)
{
    const bf16_t* Wh = WoT;
    const bf16_t* Wl = WoT + 262144;

    const int bx = blockIdx.x;             // 512 blocks: 128 mtiles x 4 ntiles
    const int r0 = (bx >> 2) * 64;
    const int c0 = (bx & 3) * 128;

    const int tid  = threadIdx.x;
    const int wave = tid >> 6;
    const int lane = tid & 63;
    const int quad = lane >> 4;
    const int l16  = lane & 15;
    const int rb = (wave >> 1) * 32;
    const int cb = (wave & 1) * 64;

    __shared__ __align__(16) bf16_t Ah[64][72];
    __shared__ __align__(16) bf16_t Al[64][72];
    __shared__ __align__(16) bf16_t Bh[128][72];
    __shared__ __align__(16) bf16_t Bl[128][72];

    f32x4 acc[2][4];
#pragma unroll
    for (int mt = 0; mt < 2; mt++)
#pragma unroll
        for (int nt = 0; nt < 4; nt++)
#pragma unroll
            for (int r = 0; r < 4; r++) acc[mt][nt][r] = 0.f;

    f32x4  xa[4];
    bf16x8 wbh[4], wbl[4];

    // prologue: K-step 0
#pragma unroll
    for (int rep = 0; rep < 4; rep++) {
        int id = rep * 256 + tid;          // 1024 ids: 64 rows x 16 f32x4 segs
        int m = id >> 4, c = id & 15;
        xa[rep] = *(const f32x4*)&Xc[(size_t)(r0 + m) * 512 + c * 4];
    }
#pragma unroll
    for (int rep = 0; rep < 4; rep++) {
        int id = rep * 256 + tid;          // 1024 ids: 128 rows x 8 k-segs
        int n = id >> 3, seg = id & 7;
        wbh[rep] = *(const bf16x8*)&Wh[(size_t)(c0 + n) * 512 + seg * 8];
        wbl[rep] = *(const bf16x8*)&Wl[(size_t)(c0 + n) * 512 + seg * 8];
    }

    for (int it = 0; it < 8; ++it) {
#pragma unroll
        for (int rep = 0; rep < 4; rep++) {
            int id = rep * 256 + tid;
            int m = id >> 4, c = id & 15;
            f32x4 v = xa[rep];
            bf16x4 hh, ll;
#pragma unroll
            for (int e = 0; e < 4; e++) {
                bf16_t hv = (bf16_t)v[e];
                hh[e] = hv;
                ll[e] = (bf16_t)(v[e] - (float)hv);
            }
            *(bf16x4*)&Ah[m][c * 4] = hh;
            *(bf16x4*)&Al[m][c * 4] = ll;
        }
#pragma unroll
        for (int rep = 0; rep < 4; rep++) {
            int id = rep * 256 + tid;
            int n = id >> 3, seg = id & 7;
            *(bf16x8*)&Bh[n][seg * 8] = wbh[rep];
            *(bf16x8*)&Bl[n][seg * 8] = wbl[rep];
        }
        __syncthreads();

        if (it < 7) {
            const int k0n = (it + 1) * 64;
#pragma unroll
            for (int rep = 0; rep < 4; rep++) {
                int id = rep * 256 + tid;
                int m = id >> 4, c = id & 15;
                xa[rep] = *(const f32x4*)&Xc[(size_t)(r0 + m) * 512 + k0n + c * 4];
            }
#pragma unroll
            for (int rep = 0; rep < 4; rep++) {
                int id = rep * 256 + tid;
                int n = id >> 3, seg = id & 7;
                wbh[rep] = *(const bf16x8*)&Wh[(size_t)(c0 + n) * 512 + k0n + seg * 8];
                wbl[rep] = *(const bf16x8*)&Wl[(size_t)(c0 + n) * 512 + k0n + seg * 8];
            }
        }

#pragma unroll
        for (int kc = 0; kc < 2; kc++) {
            bf16x8 bh[4], bl[4], ah[2], al[2];
#pragma unroll
            for (int nt = 0; nt < 4; nt++) {
                bh[nt] = *(const bf16x8*)&Bh[cb + nt * 16 + l16][kc * 32 + quad * 8];
                bl[nt] = *(const bf16x8*)&Bl[cb + nt * 16 + l16][kc * 32 + quad * 8];
            }
#pragma unroll
            for (int mt = 0; mt < 2; mt++) {
                ah[mt] = *(const bf16x8*)&Ah[rb + mt * 16 + l16][kc * 32 + quad * 8];
                al[mt] = *(const bf16x8*)&Al[rb + mt * 16 + l16][kc * 32 + quad * 8];
            }
#pragma unroll
            for (int mt = 0; mt < 2; mt++) {
#pragma unroll
                for (int nt = 0; nt < 4; nt++) {
                    acc[mt][nt] = __builtin_amdgcn_mfma_f32_16x16x32_bf16(ah[mt], bh[nt], acc[mt][nt], 0, 0, 0);
                    acc[mt][nt] = __builtin_amdgcn_mfma_f32_16x16x32_bf16(ah[mt], bl[nt], acc[mt][nt], 0, 0, 0);
                    acc[mt][nt] = __builtin_amdgcn_mfma_f32_16x16x32_bf16(al[mt], bh[nt], acc[mt][nt], 0, 0, 0);
                }
            }
        }
        __syncthreads();
    }

#pragma unroll
    for (int mt = 0; mt < 2; mt++) {
#pragma unroll
        for (int r = 0; r < 4; r++) {
            int row = r0 + rb + mt * 16 + quad * 4 + r;
#pragma unroll
            for (int nt = 0; nt < 4; nt++) {
                int col = c0 + cb + nt * 16 + l16;
                OUT[(size_t)row * 512 + col] = acc[mt][nt][r] + bo[col];
            }
        }
    }
}

// ---------------------------------------------------------------------------
// Kernel 2: attention with T14 async-stage split. grid = (bh=32, itile=32).
// LDS map (bytes), total 38912 (R12 layout, unchanged):
//   [0,     18432)  pA  [128][72] ; [18432, 27648) k_s [64][72]
//   [27648, 38912)  msw [64][88] wave-private strips (R8-verified indexing)
// ---------------------------------------------------------------------------
struct Band { int d_hi, w1, prow1, w2, e_lo, c2_0, nct1, nct2; };

__device__ __forceinline__ Band mkband(int i0, int j0)
{
    Band b;
    int d_lo = i0 - (j0 + 63);
    b.d_hi = i0 + 63 - j0;
    b.w1 = 0; b.prow1 = 0;
    if (b.d_hi >= 0) {
        int b1 = d_lo > 0 ? d_lo : 0;
        b.w1 = b.d_hi - b1 + 1;
        b.prow1 = (Tt - 1) - b.d_hi;
    }
    int dmax2 = b.d_hi < -2 ? b.d_hi : -2;
    b.w2 = 0; b.e_lo = 0;
    if (d_lo <= dmax2) {
        b.e_lo = -dmax2 - 2;
        int e_hi = -d_lo - 2;
        b.w2 = e_hi - b.e_lo + 1;
    }
    b.c2_0 = b.d_hi + 2 + b.e_lo;
    b.nct1 = (b.w1 + 15) >> 4;
    b.nct2 = (b.w2 + 15) >> 4;
    return b;
}

__global__ __launch_bounds__(256, 4)
void attn_kernel(const bf16_t* __restrict__ QU, const bf16_t* __restrict__ QV,
                 const bf16_t* __restrict__ K16, const bf16_t* __restrict__ VT16,
                 const bf16_t* __restrict__ P16, float* __restrict__ CTX)
{
    const int bh = blockIdx.x;                 // XCD locality: linear%8 = bh%8
    const int i0 = blockIdx.y * 64;
    const int b = bh >> 3, h = bh & 7;
    const int tid = threadIdx.x;
    const int wave = tid >> 6;
    const int lane = tid & 63;
    const int quad = lane >> 4;
    const int l16 = lane & 15;

    const bf16_t* qu_g = QU + (size_t)bh * Tt * Dd;
    const bf16_t* qv_g = QV + (size_t)bh * Tt * Dd;
    const bf16_t* k_g  = K16 + (size_t)bh * Tt * Dd;
    const bf16_t* vt_g = VT16 + (size_t)bh * Dd * Tt;   // [d][t]
    const bf16_t* p_g  = P16 + (size_t)bh * Tt * Dd;

    __shared__ __align__(16) char smem[38912];
    bf16_t (*pA)[72]  = (bf16_t (*)[72])(smem);           // 128 rows (P band)
    bf16_t (*k_s)[72] = (bf16_t (*)[72])(smem + 18432);   // 64 rows
    bf16_t (*msw)[88] = (bf16_t (*)[88])(smem + 27648);   // 64 rows, strip-local

    const int off_w = 48 - wave * 16;          // strip-local = absolute - off_w
    const int cmin = 48 - wave * 16;           // absolute strip window
    const int cmax = 126 - wave * 16;

    // staging id decomposition (same for K and P paths)
    const int srow = tid >> 3;                 // 0..31
    const int sseg = tid & 7;                  // 0..7

    // A-operand fragments, direct global loads: A[m=l16][k=quad*8+e]
    const int qrow = i0 + wave * 16 + l16;
    const int qrow2 = (qrow + 1 > Tt - 1) ? (Tt - 1) : (qrow + 1);  // clamped row never gathered
    bf16x8 aq[2], av1[2], av2[2];
#pragma unroll
    for (int kc = 0; kc < 2; kc++) {
        aq[kc]  = *(const bf16x8*)(qu_g + (size_t)qrow  * Dd + kc * 32 + quad * 8);
        av1[kc] = *(const bf16x8*)(qv_g + (size_t)qrow  * Dd + kc * 32 + quad * 8);
        av2[kc] = *(const bf16x8*)(qv_g + (size_t)qrow2 * Dd + kc * 32 + quad * 8);
    }

    float lsum[4];
    f32x4 accO[4];
#pragma unroll
    for (int r = 0; r < 4; r++) lsum[r] = 0.f;
#pragma unroll
    for (int dt = 0; dt < 4; dt++)
#pragma unroll
        for (int r = 0; r < 4; r++) accO[dt][r] = 0.f;

    // --- T14 prefetch registers (named scalars; no arrays -> no scratch) ---
    f32x4 kr0, kr1, pr0, pr1, pr2, pr3;
    Band bp = mkband(i0, 0);
    {
        kr0 = *(const f32x4*)(k_g + (size_t)(0 + srow) * Dd + sseg * 8);
        kr1 = *(const f32x4*)(k_g + (size_t)(0 + srow + 32) * Dd + sseg * 8);
        int r0_ = srow,      s0 = (r0_ < bp.w1) ? bp.prow1 + r0_ : bp.e_lo + r0_ - bp.w1;
        int r1_ = srow + 32, s1 = (r1_ < bp.w1) ? bp.prow1 + r1_ : bp.e_lo + r1_ - bp.w1;
        int r2_ = srow + 64, s2 = (r2_ < bp.w1) ? bp.prow1 + r2_ : bp.e_lo + r2_ - bp.w1;
        int r3_ = srow + 96, s3 = (r3_ < bp.w1) ? bp.prow1 + r3_ : bp.e_lo + r3_ - bp.w1;
        if (s0 > Tt - 1) s0 = Tt - 1;
        if (s1 > Tt - 1) s1 = Tt - 1;
        if (s2 > Tt - 1) s2 = Tt - 1;
        if (s3 > Tt - 1) s3 = Tt - 1;
        pr0 = *(const f32x4*)(p_g + (size_t)s0 * Dd + sseg * 8);
        pr1 = *(const f32x4*)(p_g + (size_t)s1 * Dd + sseg * 8);
        pr2 = *(const f32x4*)(p_g + (size_t)s2 * Dd + sseg * 8);
        pr3 = *(const f32x4*)(p_g + (size_t)s3 * Dd + sseg * 8);
    }

    for (int j0 = 0; j0 < Tt; j0 += 64) {
        const Band bc = bp;

        // write prefetched regs to LDS (same addresses/guards as staged path)
        *(f32x4*)&k_s[srow][sseg * 8]      = kr0;
        *(f32x4*)&k_s[srow + 32][sseg * 8] = kr1;
        {
            int wtot = bc.w1 + bc.w2;
            if (srow < wtot)      *(f32x4*)&pA[srow][sseg * 8]      = pr0;
            if (srow + 32 < wtot) *(f32x4*)&pA[srow + 32][sseg * 8] = pr1;
            if (srow + 64 < wtot) *(f32x4*)&pA[srow + 64][sseg * 8] = pr2;
            if (srow + 96 < wtot) *(f32x4*)&pA[srow + 96][sseg * 8] = pr3;
        }
        __syncthreads();

        // issue next tile's K/P loads now; they fly under the compute below
        if (j0 + 64 < Tt) {
            bp = mkband(i0, j0 + 64);
            kr0 = *(const f32x4*)(k_g + (size_t)(j0 + 64 + srow) * Dd + sseg * 8);
            kr1 = *(const f32x4*)(k_g + (size_t)(j0 + 64 + srow + 32) * Dd + sseg * 8);
            int r0_ = srow,      s0 = (r0_ < bp.w1) ? bp.prow1 + r0_ : bp.e_lo + r0_ - bp.w1;
            int r1_ = srow + 32, s1 = (r1_ < bp.w1) ? bp.prow1 + r1_ : bp.e_lo + r1_ - bp.w1;
            int r2_ = srow + 64, s2 = (r2_ < bp.w1) ? bp.prow1 + r2_ : bp.e_lo + r2_ - bp.w1;
            int r3_ = srow + 96, s3 = (r3_ < bp.w1) ? bp.prow1 + r3_ : bp.e_lo + r3_ - bp.w1;
            if (s0 > Tt - 1) s0 = Tt - 1;
            if (s1 > Tt - 1) s1 = Tt - 1;
            if (s2 > Tt - 1) s2 = Tt - 1;
            if (s3 > Tt - 1) s3 = Tt - 1;
            pr0 = *(const f32x4*)(p_g + (size_t)s0 * Dd + sseg * 8);
            pr1 = *(const f32x4*)(p_g + (size_t)s1 * Dd + sseg * 8);
            pr2 = *(const f32x4*)(p_g + (size_t)s2 * Dd + sseg * 8);
            pr3 = *(const f32x4*)(p_g + (size_t)s3 * Dd + sseg * 8);
        }

        // content scores
        f32x4 accS[4];
#pragma unroll
        for (int nt = 0; nt < 4; nt++) {
            f32x4 acc = {0.f, 0.f, 0.f, 0.f};
#pragma unroll
            for (int kc = 0; kc < 2; kc++) {
                bf16x8 bk8 = *(const bf16x8*)&k_s[nt * 16 + l16][kc * 32 + quad * 8];
                acc = __builtin_amdgcn_mfma_f32_16x16x32_bf16(aq[kc], bk8, acc, 0, 0, 0);
            }
            accS[nt] = acc;
        }

        // banded pos matmul -> strip-local skewed store (wave-private)
        for (int ct = 0; ct < bc.nct1 + bc.nct2; ct++) {
            bool b2 = ct >= bc.nct1;
            int rb_ = b2 ? (bc.w1 + (ct - bc.nct1) * 16) : (ct * 16);
            int cb_ = b2 ? (bc.c2_0 + (ct - bc.nct1) * 16) : (ct * 16);
            if (cb_ > cmax || cb_ + 15 < cmin) continue;
            f32x4 acc = {0.f, 0.f, 0.f, 0.f};
#pragma unroll
            for (int kc = 0; kc < 2; kc++) {
                bf16x8 bp8 = *(const bf16x8*)&pA[rb_ + l16][kc * 32 + quad * 8];
                acc = b2 ? __builtin_amdgcn_mfma_f32_16x16x32_bf16(av2[kc], bp8, acc, 0, 0, 0)
                         : __builtin_amdgcn_mfma_f32_16x16x32_bf16(av1[kc], bp8, acc, 0, 0, 0);
            }
            int colp = cb_ + l16 - off_w;          // strip-local
            if ((unsigned)colp < 80u) {
#pragma unroll
                for (int r = 0; r < 4; r++)
                    msw[wave * 16 + quad * 4 + r][colp] = (bf16_t)acc[r];
            }
        }
        // zero column for dd == -1 (strip-local)
        {
            int zcl = bc.d_hi + 1 - off_w;
            if ((unsigned)zcl < 80u && quad == 0)
                msw[wave * 16 + l16][zcl] = (bf16_t)0.f;
        }

        // gather all 16 (no aliasing stores in between), then write weights
        float wv[4][4];
#pragma unroll
        for (int nt = 0; nt < 4; nt++) {
#pragma unroll
            for (int r = 0; r < 4; r++) {
                float pos = (float)msw[wave * 16 + quad * 4 + r]
                                    [nt * 16 + l16 + 15 - (quad * 4 + r)];
                float x = accS[nt][r] + pos;
                float a = fminf(fmaf(x, 0.18033688f, -17.3123405f), 120.0f);
                float w = exp2f(a);
                lsum[r] += w;
                wv[nt][r] = w;
            }
        }
#pragma unroll
        for (int nt = 0; nt < 4; nt++)
#pragma unroll
            for (int r = 0; r < 4; r++)
                msw[wave * 16 + quad * 4 + r][nt * 16 + l16] = (bf16_t)wv[nt][r];

        // O += W @ V : A from own msw strip, B direct from VT ([d][t])
#pragma unroll
        for (int kc = 0; kc < 2; kc++) {
            bf16x8 aw = *(const bf16x8*)&msw[wave * 16 + l16][kc * 32 + quad * 8];
#pragma unroll
            for (int dt = 0; dt < 4; dt++) {
                bf16x8 bv8 = *(const bf16x8*)(vt_g + (size_t)(dt * 16 + l16) * Tt + j0 + kc * 32 + quad * 8);
                accO[dt] = __builtin_amdgcn_mfma_f32_16x16x32_bf16(aw, bv8, accO[dt], 0, 0, 0);
            }
        }
        __syncthreads();  // protect k_s/pA before next write phase
    }

#pragma unroll
    for (int r = 0; r < 4; r++) {
#pragma unroll
        for (int off = 1; off < 16; off <<= 1) lsum[r] += __shfl_xor(lsum[r], off, 64);
    }

#pragma unroll
    for (int r = 0; r < 4; r++) {
        int il = wave * 16 + quad * 4 + r;
        int ig = i0 + il;
        float inv = 1.0f / lsum[r];
#pragma unroll
        for (int dt = 0; dt < 4; dt++) {
            CTX[((size_t)(b * Tt + ig)) * Cc + h * Dd + dt * 16 + l16] = accO[dt][r] * inv;
        }
    }
}

// ---------------------------------------------------------------------------
extern "C" void kernel_launch(void* const* d_in, const int* in_sizes, int n_in,
                              void* d_out, int out_size, void* d_ws, size_t ws_size,
                              hipStream_t stream)
{
    const float* query = (const float*)d_in[0];
    const float* key   = (const float*)d_in[1];
    const float* value = (const float*)d_in[2];
    const float* pemb  = (const float*)d_in[3];
    const float* Wq    = (const float*)d_in[4];
    const float* bq    = (const float*)d_in[5];
    const float* Wk    = (const float*)d_in[6];
    const float* bk    = (const float*)d_in[7];
    const float* Wv    = (const float*)d_in[8];
    const float* bv    = (const float*)d_in[9];
    const float* Wpos  = (const float*)d_in[10];
    const float* pbu   = (const float*)d_in[11];
    const float* pbv   = (const float*)d_in[12];
    const float* Wo    = (const float*)d_in[13];
    const float* bo    = (const float*)d_in[14];

    const size_t NE = (size_t)Bb * Hh * Tt * Dd;  // 4,194,304 per tensor
    bf16_t* QU   = (bf16_t*)d_ws;
    bf16_t* QV   = QU + NE;
    bf16_t* K16  = QV + NE;
    bf16_t* VT16 = K16 + NE;
    bf16_t* P16  = VT16 + NE;
    float*  CTX  = (float*)(P16 + NE);            // ws >= 56 MB (unchanged)

    // W^T hi/lo planes overlaid on dead regions (no extra workspace):
    //  - WT4 (Wq,Wk,Wv,Wpos; 4 MB) in CTX region: dead until attn writes CTX.
    //  - WoT (1 MB) in QU region: written AFTER attn (QU dead by then).
    bf16_t* WT4 = (bf16_t*)CTX;
    bf16_t* WoT = (bf16_t*)QU;

    // prepass A: Wq/Wk/Wv/Wpos -> transposed hi/lo bf16 planes
    wsplit_kernel<<<dim3(64, 4), 256, 0, stream>>>(Wq, Wk, Wv, Wpos, Wo, WT4, WoT, -1);

    // QKVP projections (z = blockIdx.z)
    split_gemm_kernel<<<dim3(256, 1, 4), 256, 0, stream>>>(
        query, key, value, pemb, WT4,
        bq, bk, bv, pbu, pbv, QU, QV, K16, VT16, P16);

    attn_kernel<<<dim3(32, 32), 256, 0, stream>>>(QU, QV, K16, VT16, P16, CTX);

    // prepass B: Wo -> WoT (QU region now dead)
    wsplit_kernel<<<dim3(64, 1), 256, 0, stream>>>(Wq, Wk, Wv, Wpos, Wo, WT4, WoT, 4);

    // output projection: 64x128 tiles, 512 blocks
    out_gemm_kernel<<<dim3(512), 256, 0, stream>>>(CTX, WoT, bo, (float*)d_out);
}